// Round 3
// baseline (1604.104 us; speedup 1.0000x reference)
//
#include <hip/hip_runtime.h>

#define TT 2048      // tokens (B*S)
#define HD 2048      // hidden
#define FD 1408      // per-expert ffn
#define SFD 5632     // shared ffn
#define NE 8         // experts
#define BM 128
#define BN 128
#define BK 32

using f32x4 = __attribute__((ext_vector_type(4))) float;
using s16x8 = __attribute__((ext_vector_type(8))) short;

__device__ __forceinline__ unsigned short f2bf(float f) {
    union { float f; unsigned u; } v; v.f = f;
    unsigned r = v.u + 0x7fff + ((v.u >> 16) & 1);   // RNE
    return (unsigned short)(r >> 16);
}
__device__ __forceinline__ float bf2f(unsigned short u) {
    union { unsigned u; float f; } v; v.u = ((unsigned)u) << 16;
    return v.f;
}

__device__ __forceinline__ void gload16(const void* g, void* l) {
    __builtin_amdgcn_global_load_lds(
        (const __attribute__((address_space(1))) unsigned*)g,
        (__attribute__((address_space(3))) unsigned*)l, 16, 0, 0);
}

// ---- fp32 -> bf16 activation conversion -------------------------------------
__global__ void cvt_kernel(const float* __restrict__ x, unsigned short* __restrict__ xb) {
    size_t i = ((size_t)blockIdx.x * 256 + threadIdx.x) * 8;
    float4 f0 = *(const float4*)(x + i);
    float4 f1 = *(const float4*)(x + i + 4);
    s16x8 v;
    v[0]=(short)f2bf(f0.x); v[1]=(short)f2bf(f0.y); v[2]=(short)f2bf(f0.z); v[3]=(short)f2bf(f0.w);
    v[4]=(short)f2bf(f1.x); v[5]=(short)f2bf(f1.y); v[6]=(short)f2bf(f1.z); v[7]=(short)f2bf(f1.w);
    *(s16x8*)(xb + i) = v;
}

// ---- router: fp32 softmax, top-2, expert lists, shared sigmoid gate ---------
__global__ void router_kernel(const float* __restrict__ x, const float* __restrict__ gw,
                              const float* __restrict__ segw,
                              int* counts, int* tlist, float* wlist, float* gateval,
                              int* selpos) {
    int wave = threadIdx.x >> 6;
    int lane = threadIdx.x & 63;
    int t = blockIdx.x * 4 + wave;
    float acc[9];
    #pragma unroll
    for (int i = 0; i < 9; ++i) acc[i] = 0.f;
    const float* xrow = x + (size_t)t * HD;
    for (int h = lane; h < HD; h += 64) {
        float xv = xrow[h];
        #pragma unroll
        for (int e = 0; e < NE; ++e) acc[e] += xv * gw[e * HD + h];
        acc[8] += xv * segw[h];
    }
    #pragma unroll
    for (int i = 0; i < 9; ++i) {
        float v = acc[i];
        #pragma unroll
        for (int s = 32; s > 0; s >>= 1) v += __shfl_xor(v, s);
        acc[i] = v;
    }
    if (lane == 0) {
        float m = acc[0];
        #pragma unroll
        for (int e = 1; e < NE; ++e) m = fmaxf(m, acc[e]);
        float p[NE], sum = 0.f;
        #pragma unroll
        for (int e = 0; e < NE; ++e) { p[e] = expf(acc[e] - m); sum += p[e]; }
        float inv = 1.f / sum;
        int b1 = 0, b2 = -1; float v1 = p[0], v2 = -1.f;
        #pragma unroll
        for (int e = 1; e < NE; ++e) {
            if (p[e] > v1) { v2 = v1; b2 = b1; v1 = p[e]; b1 = e; }
            else if (p[e] > v2) { v2 = p[e]; b2 = e; }
        }
        v1 *= inv; v2 *= inv;
        int s1 = atomicAdd(&counts[b1], 1); tlist[b1 * TT + s1] = t; wlist[b1 * TT + s1] = v1;
        int s2 = atomicAdd(&counts[b2], 1); tlist[b2 * TT + s2] = t; wlist[b2 * TT + s2] = v2;
        selpos[2 * t]     = b1 * TT + s1;
        selpos[2 * t + 1] = b2 * TT + s2;
        gateval[t] = 1.f / (1.f + expf(-acc[8]));
    }
}

__global__ void prefix_kernel(const int* counts, int* offsets) {
    if (threadIdx.x == 0) {
        int s = 0;
        for (int e = 0; e < NE; ++e) { offsets[e] = s; s += counts[e]; }
    }
}

// ---- combine: out[t] += w0*robuf[row0] + w1*robuf[row1] ---------------------
__global__ void combine_kernel(const int* __restrict__ selpos, const float* __restrict__ wlist,
                               const int* __restrict__ offsets,
                               const unsigned short* __restrict__ robuf, float* __restrict__ out) {
    int t = blockIdx.x;
    int p0 = selpos[2 * t], p1 = selpos[2 * t + 1];
    float w0 = wlist[p0], w1 = wlist[p1];
    int r0 = offsets[p0 >> 11] + (p0 & (TT - 1));   // TT = 2048 = 1<<11
    int r1 = offsets[p1 >> 11] + (p1 & (TT - 1));
    int c = threadIdx.x * 8;
    s16x8 a = *(const s16x8*)(robuf + (size_t)r0 * HD + c);
    s16x8 b = *(const s16x8*)(robuf + (size_t)r1 * HD + c);
    float* op = out + (size_t)t * HD + c;
    float4 o0 = *(float4*)op, o1 = *(float4*)(op + 4);
    o0.x += w0 * bf2f((unsigned short)a[0]) + w1 * bf2f((unsigned short)b[0]);
    o0.y += w0 * bf2f((unsigned short)a[1]) + w1 * bf2f((unsigned short)b[1]);
    o0.z += w0 * bf2f((unsigned short)a[2]) + w1 * bf2f((unsigned short)b[2]);
    o0.w += w0 * bf2f((unsigned short)a[3]) + w1 * bf2f((unsigned short)b[3]);
    o1.x += w0 * bf2f((unsigned short)a[4]) + w1 * bf2f((unsigned short)b[4]);
    o1.y += w0 * bf2f((unsigned short)a[5]) + w1 * bf2f((unsigned short)b[5]);
    o1.z += w0 * bf2f((unsigned short)a[6]) + w1 * bf2f((unsigned short)b[6]);
    o1.w += w0 * bf2f((unsigned short)a[7]) + w1 * bf2f((unsigned short)b[7]);
    *(float4*)op = o0; *(float4*)(op + 4) = o1;
}

// ---- pipelined GEMM: C[M,N(,x2)] = A[M,K](bf16) @ B[N,K](fp32->bf16)^T ------
// grid: x = M-tile (fast-varying -> co-resident blocks share one B panel,
//        weights fetched from HBM exactly once), y = N-tile, z = expert.
// double-buffered LDS; A via global_load_lds; B reg-staged fp32->bf16,
// ds_write after MFMA (T14 issue-early/write-late).
// EPI 0: C = bf16(silu(g)*u), fused gate+up (NB=2)
// EPI 1: C = bf16(acc)                      (routed down -> robuf)
// EPI 2: atomicAdd out[tok] += w*acc        (fallback if ws too small)
// EPI 3: out[row] = gateval[row]*acc        (shared down)
template<int NB, int EPI, bool GATHER>
__global__ __launch_bounds__(256)
void gemm2(const unsigned short* __restrict__ A, int lda,
           const float* __restrict__ B0, const float* __restrict__ B1,
           size_t eStrideB, int ldb, int K, int Mfixed,
           const int* __restrict__ counts, const int* __restrict__ offsets,
           const int* __restrict__ tlist, const float* __restrict__ wlist,
           unsigned short* __restrict__ C, int ldc,
           const float* __restrict__ gateval, float* __restrict__ out, int ldout) {
    __shared__ s16x8 As[2][512];
    __shared__ s16x8 Bs[NB][2][512];

    int e = blockIdx.z;
    int M = counts ? counts[e] : Mfixed;
    int m0 = blockIdx.x * BM;          // M fast-varying
    if (M == 0 || m0 >= M) return;
    int n0 = blockIdx.y * BN;
    int row_off = offsets ? offsets[e] : 0;
    const float* Bp0 = B0 + (size_t)e * eStrideB;
    const float* Bp1 = (NB == 2) ? B1 + (size_t)e * eStrideB : B0;

    int tid = threadIdx.x;
    int lane = tid & 63, w = tid >> 6;

    // A staging pointers: lane covers row it*64+lane, wave w covers k-group w
    const unsigned short* aptr[2];
    #pragma unroll
    for (int it = 0; it < 2; ++it) {
        int ar = m0 + it * 64 + lane; if (ar > M - 1) ar = M - 1;
        size_t grow;
        if constexpr (GATHER) grow = (size_t)tlist[e * TT + ar];
        else                  grow = (size_t)(row_off + ar);
        aptr[it] = A + grow * (size_t)lda;
    }
    // B staging pointers: thread pair covers one row's 32 k-floats
    int srow = tid >> 1, kg0 = (tid & 1) * 2;
    const float* bptr0 = Bp0 + (size_t)(n0 + srow) * ldb + kg0 * 8;
    const float* bptr1 = Bp1 + (size_t)(n0 + srow) * ldb + kg0 * 8;

    int wm = (w >> 1) * 64, wn = (w & 1) * 64;
    int grp = lane >> 4, l16 = lane & 15;

    f32x4 acc[NB][4][4];
    f32x4 zero = {0.f, 0.f, 0.f, 0.f};
    #pragma unroll
    for (int m = 0; m < NB; ++m)
        #pragma unroll
        for (int mi = 0; mi < 4; ++mi)
            #pragma unroll
            for (int ni = 0; ni < 4; ++ni) acc[m][mi][ni] = zero;

    float4 breg[NB][4];

    auto stageA = [&](int buf, int k0) {
        #pragma unroll
        for (int it = 0; it < 2; ++it)
            gload16(aptr[it] + k0 + w * 8, (void*)&As[buf][w * 128 + it * 64]);
    };
    auto loadB = [&](int k0) {
        #pragma unroll
        for (int j = 0; j < 2; ++j) {
            breg[0][j * 2]     = *(const float4*)(bptr0 + k0 + j * 8);
            breg[0][j * 2 + 1] = *(const float4*)(bptr0 + k0 + j * 8 + 4);
            if constexpr (NB == 2) {
                breg[1][j * 2]     = *(const float4*)(bptr1 + k0 + j * 8);
                breg[1][j * 2 + 1] = *(const float4*)(bptr1 + k0 + j * 8 + 4);
            }
        }
    };
    auto writeB = [&](int buf) {
        #pragma unroll
        for (int m = 0; m < NB; ++m)
            #pragma unroll
            for (int j = 0; j < 2; ++j) {
                float4 f0 = breg[m][j * 2], f1 = breg[m][j * 2 + 1];
                s16x8 v;
                v[0]=(short)f2bf(f0.x); v[1]=(short)f2bf(f0.y); v[2]=(short)f2bf(f0.z); v[3]=(short)f2bf(f0.w);
                v[4]=(short)f2bf(f1.x); v[5]=(short)f2bf(f1.y); v[6]=(short)f2bf(f1.z); v[7]=(short)f2bf(f1.w);
                Bs[m][buf][(kg0 + j) * 128 + srow] = v;
            }
    };

    stageA(0, 0); loadB(0); writeB(0);
    __syncthreads();

    int NT = K / BK;
    for (int kt = 0; kt < NT; ++kt) {
        int cur = kt & 1;
        bool more = (kt + 1 < NT);
        if (more) { stageA(cur ^ 1, (kt + 1) * BK); loadB((kt + 1) * BK); }
        s16x8 af[4];
        #pragma unroll
        for (int i = 0; i < 4; ++i) af[i] = As[cur][grp * 128 + wm + i * 16 + l16];
        #pragma unroll
        for (int ni = 0; ni < 4; ++ni) {
            #pragma unroll
            for (int m = 0; m < NB; ++m) {
                s16x8 bf = Bs[m][cur][grp * 128 + wn + ni * 16 + l16];
                #pragma unroll
                for (int mi = 0; mi < 4; ++mi)
                    acc[m][mi][ni] = __builtin_amdgcn_mfma_f32_16x16x32_bf16(af[mi], bf, acc[m][mi][ni], 0, 0, 0);
            }
        }
        if (more) writeB(cur ^ 1);
        __syncthreads();
    }

    // epilogue: frag row = (lane>>4)*4 + r, col = lane&15
    #pragma unroll
    for (int mi = 0; mi < 4; ++mi) {
        #pragma unroll
        for (int r = 0; r < 4; ++r) {
            int mrow = m0 + wm + mi * 16 + (lane >> 4) * 4 + r;
            if (mrow >= M) continue;
            #pragma unroll
            for (int ni = 0; ni < 4; ++ni) {
                int col = n0 + wn + ni * 16 + l16;
                if constexpr (EPI == 0) {
                    float g = acc[0][mi][ni][r], u = acc[1][mi][ni][r];
                    C[(size_t)(row_off + mrow) * ldc + col] = f2bf(g * u / (1.f + __expf(-g)));
                } else if constexpr (EPI == 1) {
                    C[(size_t)(row_off + mrow) * ldc + col] = f2bf(acc[0][mi][ni][r]);
                } else if constexpr (EPI == 2) {
                    int tok = tlist[e * TT + mrow]; float wv = wlist[e * TT + mrow];
                    atomicAdd(out + (size_t)tok * ldout + col, wv * acc[0][mi][ni][r]);
                } else {
                    out[(size_t)mrow * ldout + col] = gateval[mrow] * acc[0][mi][ni][r];
                }
            }
        }
    }
}

extern "C" void kernel_launch(void* const* d_in, const int* in_sizes, int n_in,
                              void* d_out, int out_size, void* d_ws, size_t ws_size,
                              hipStream_t stream) {
    const float* x    = (const float*)d_in[0];
    const float* gw   = (const float*)d_in[1];
    const float* gpw  = (const float*)d_in[2];
    const float* upw  = (const float*)d_in[3];
    const float* dpw  = (const float*)d_in[4];
    const float* sgw  = (const float*)d_in[5];
    const float* suw  = (const float*)d_in[6];
    const float* sdw  = (const float*)d_in[7];
    const float* segw = (const float*)d_in[8];
    float* out = (float*)d_out;
    char* ws = (char*)d_ws;

    int*   counts  = (int*)(ws + 0);
    int*   offsets = (int*)(ws + 64);
    int*   tlist   = (int*)(ws + 256);        // 64 KB
    float* wlist   = (float*)(ws + 65792);    // 64 KB
    float* gateval = (float*)(ws + 131328);   // 8 KB
    int*   selpos  = (int*)(ws + 139520);     // 16 KB
    unsigned short* xb    = (unsigned short*)(ws + 155904);     // 8 MB bf16 activations
    unsigned short* gbuf  = (unsigned short*)(ws + 8544512);    // 23.1 MB (shared) / 11.5 MB (routed)
    unsigned short* robuf = (unsigned short*)(ws + 20078848);   // 16.8 MB, after routed gbuf
    size_t needed = 20078848 + (size_t)4096 * HD * 2;           // ~36.9 MB

    hipMemsetAsync(counts, 0, 64, stream);
    cvt_kernel<<<dim3(TT * HD / (256 * 8)), 256, 0, stream>>>(x, xb);
    router_kernel<<<dim3(TT / 4), 256, 0, stream>>>(x, gw, segw, counts, tlist, wlist, gateval, selpos);
    prefix_kernel<<<dim3(1), 64, 0, stream>>>(counts, offsets);

    // shared expert: fused gate+up -> gbuf, then gated down -> out (writes all of out)
    gemm2<2, 0, false><<<dim3(TT / BM, SFD / BN, 1), 256, 0, stream>>>(
        xb, HD, sgw, suw, 0, HD, HD, TT, nullptr, nullptr, nullptr, nullptr, gbuf, SFD, nullptr, nullptr, 0);
    gemm2<1, 3, false><<<dim3(TT / BM, HD / BN, 1), 256, 0, stream>>>(
        gbuf, SFD, sdw, nullptr, 0, SFD, SFD, TT, nullptr, nullptr, nullptr, nullptr, nullptr, 0, gateval, out, HD);

    // routed experts: fused gate+up -> gbuf (expert-sorted rows)
    gemm2<2, 0, true><<<dim3(TT / BM, FD / BN, NE), 256, 0, stream>>>(
        xb, HD, gpw, upw, (size_t)FD * HD, HD, HD, 0, counts, offsets, tlist, nullptr, gbuf, FD, nullptr, nullptr, 0);

    if (ws_size >= needed) {
        // down -> robuf (no atomics), then per-token combine
        gemm2<1, 1, false><<<dim3(TT / BM, HD / BN, NE), 256, 0, stream>>>(
            gbuf, FD, dpw, nullptr, (size_t)HD * FD, FD, FD, 0, counts, offsets, nullptr, nullptr, robuf, HD, nullptr, nullptr, 0);
        combine_kernel<<<dim3(TT), 256, 0, stream>>>(selpos, wlist, offsets, robuf, out);
    } else {
        // fallback: atomic scatter-add (round-1 behavior)
        gemm2<1, 2, false><<<dim3(TT / BM, HD / BN, NE), 256, 0, stream>>>(
            gbuf, FD, dpw, nullptr, (size_t)HD * FD, FD, FD, 0, counts, offsets, tlist, wlist, nullptr, 0, nullptr, out, HD);
    }
}

// Round 4
// 1137.507 us; speedup vs baseline: 1.4102x; 1.4102x over previous
//
#include <hip/hip_runtime.h>

#define TT 2048      // tokens (B*S)
#define HD 2048      // hidden
#define FD 1408      // per-expert ffn
#define SFD 5632     // shared ffn
#define NE 8         // experts
#define BM 128
#define BN 128
#define BK 32

using f32x4 = __attribute__((ext_vector_type(4))) float;
using s16x8 = __attribute__((ext_vector_type(8))) short;

__device__ __forceinline__ unsigned short f2bf(float f) {
    union { float f; unsigned u; } v; v.f = f;
    unsigned r = v.u + 0x7fff + ((v.u >> 16) & 1);   // RNE
    return (unsigned short)(r >> 16);
}
__device__ __forceinline__ float bf2f(unsigned short u) {
    union { unsigned u; float f; } v; v.u = ((unsigned)u) << 16;
    return v.f;
}
// pack two fp32 -> bf16x2 (round-half-up, err <= 0.5 ulp); compiler emits v_perm
__device__ __forceinline__ unsigned cvt2(float a, float b) {
    union { float f; unsigned u; } va, vb; va.f = a; vb.f = b;
    unsigned ra = va.u + 0x8000u, rb = vb.u + 0x8000u;
    return (rb & 0xffff0000u) | (ra >> 16);
}
__device__ __forceinline__ s16x8 pack8(f32x4 h0, f32x4 h1) {
    union { unsigned u[4]; s16x8 s; } r;
    r.u[0] = cvt2(h0[0], h0[1]); r.u[1] = cvt2(h0[2], h0[3]);
    r.u[2] = cvt2(h1[0], h1[1]); r.u[3] = cvt2(h1[2], h1[3]);
    return r.s;
}

__device__ __forceinline__ void gload16(const void* g, void* l) {
    __builtin_amdgcn_global_load_lds(
        (const __attribute__((address_space(1))) unsigned*)g,
        (__attribute__((address_space(3))) unsigned*)l, 16, 0, 0);
}

// ---- fp32 -> bf16 activation conversion -------------------------------------
__global__ void cvt_kernel(const float* __restrict__ x, unsigned short* __restrict__ xb) {
    size_t i = ((size_t)blockIdx.x * 256 + threadIdx.x) * 8;
    float4 f0 = *(const float4*)(x + i);
    float4 f1 = *(const float4*)(x + i + 4);
    s16x8 v;
    v[0]=(short)f2bf(f0.x); v[1]=(short)f2bf(f0.y); v[2]=(short)f2bf(f0.z); v[3]=(short)f2bf(f0.w);
    v[4]=(short)f2bf(f1.x); v[5]=(short)f2bf(f1.y); v[6]=(short)f2bf(f1.z); v[7]=(short)f2bf(f1.w);
    *(s16x8*)(xb + i) = v;
}

// ---- router: fp32 softmax, top-2, expert lists, shared sigmoid gate ---------
__global__ void router_kernel(const float* __restrict__ x, const float* __restrict__ gw,
                              const float* __restrict__ segw,
                              int* counts, int* tlist, float* wlist, float* gateval,
                              int* selpos) {
    int wave = threadIdx.x >> 6;
    int lane = threadIdx.x & 63;
    int t = blockIdx.x * 4 + wave;
    float acc[9];
    #pragma unroll
    for (int i = 0; i < 9; ++i) acc[i] = 0.f;
    const float* xrow = x + (size_t)t * HD;
    for (int h = lane; h < HD; h += 64) {
        float xv = xrow[h];
        #pragma unroll
        for (int e = 0; e < NE; ++e) acc[e] += xv * gw[e * HD + h];
        acc[8] += xv * segw[h];
    }
    #pragma unroll
    for (int i = 0; i < 9; ++i) {
        float v = acc[i];
        #pragma unroll
        for (int s = 32; s > 0; s >>= 1) v += __shfl_xor(v, s);
        acc[i] = v;
    }
    if (lane == 0) {
        float m = acc[0];
        #pragma unroll
        for (int e = 1; e < NE; ++e) m = fmaxf(m, acc[e]);
        float p[NE], sum = 0.f;
        #pragma unroll
        for (int e = 0; e < NE; ++e) { p[e] = expf(acc[e] - m); sum += p[e]; }
        float inv = 1.f / sum;
        int b1 = 0, b2 = -1; float v1 = p[0], v2 = -1.f;
        #pragma unroll
        for (int e = 1; e < NE; ++e) {
            if (p[e] > v1) { v2 = v1; b2 = b1; v1 = p[e]; b1 = e; }
            else if (p[e] > v2) { v2 = p[e]; b2 = e; }
        }
        v1 *= inv; v2 *= inv;
        int s1 = atomicAdd(&counts[b1], 1); tlist[b1 * TT + s1] = t; wlist[b1 * TT + s1] = v1;
        int s2 = atomicAdd(&counts[b2], 1); tlist[b2 * TT + s2] = t; wlist[b2 * TT + s2] = v2;
        selpos[2 * t]     = b1 * TT + s1;
        selpos[2 * t + 1] = b2 * TT + s2;
        gateval[t] = 1.f / (1.f + expf(-acc[8]));
    }
}

__global__ void prefix_kernel(const int* counts, int* offsets) {
    if (threadIdx.x == 0) {
        int s = 0;
        for (int e = 0; e < NE; ++e) { offsets[e] = s; s += counts[e]; }
    }
}

// ---- combine: out[t] += w0*robuf[row0] + w1*robuf[row1] ---------------------
__global__ void combine_kernel(const int* __restrict__ selpos, const float* __restrict__ wlist,
                               const int* __restrict__ offsets,
                               const unsigned short* __restrict__ robuf, float* __restrict__ out) {
    int t = blockIdx.x;
    int p0 = selpos[2 * t], p1 = selpos[2 * t + 1];
    float w0 = wlist[p0], w1 = wlist[p1];
    int r0 = offsets[p0 >> 11] + (p0 & (TT - 1));   // TT = 2048 = 1<<11
    int r1 = offsets[p1 >> 11] + (p1 & (TT - 1));
    int c = threadIdx.x * 8;
    s16x8 a = *(const s16x8*)(robuf + (size_t)r0 * HD + c);
    s16x8 b = *(const s16x8*)(robuf + (size_t)r1 * HD + c);
    float* op = out + (size_t)t * HD + c;
    float4 o0 = *(float4*)op, o1 = *(float4*)(op + 4);
    o0.x += w0 * bf2f((unsigned short)a[0]) + w1 * bf2f((unsigned short)b[0]);
    o0.y += w0 * bf2f((unsigned short)a[1]) + w1 * bf2f((unsigned short)b[1]);
    o0.z += w0 * bf2f((unsigned short)a[2]) + w1 * bf2f((unsigned short)b[2]);
    o0.w += w0 * bf2f((unsigned short)a[3]) + w1 * bf2f((unsigned short)b[3]);
    o1.x += w0 * bf2f((unsigned short)a[4]) + w1 * bf2f((unsigned short)b[4]);
    o1.y += w0 * bf2f((unsigned short)a[5]) + w1 * bf2f((unsigned short)b[5]);
    o1.z += w0 * bf2f((unsigned short)a[6]) + w1 * bf2f((unsigned short)b[6]);
    o1.w += w0 * bf2f((unsigned short)a[7]) + w1 * bf2f((unsigned short)b[7]);
    *(float4*)op = o0; *(float4*)(op + 4) = o1;
}

// ---- m97-style GEMM: C[M,N] = A[M,K](bf16) @ B[N,K](fp32)^T -----------------
// grid: x = N-tile (round-1 ordering, empirically best), y = M-tile, z = expert.
// Both A and B staged via global_load_lds (B as raw fp32, no reg round-trip),
// double-buffered, one __syncthreads (vmcnt drain) per K-step, next-tile loads
// issued right after the barrier so they fly under frag-reads + MFMA.
// fp32->bf16 happens at fragment build (cheap round-half-up pack).
// LDS: A 2x8KB + B 2x16KB = 48 KB -> 3 blocks/CU.
// EPI 0: C = bf16(acc)               (gate store; also routed down -> robuf)
// EPI 1: C = bf16(silu(C)*acc)       (up, SwiGLU RMW in-place)
// EPI 2: atomicAdd out[tok] += w*acc (fallback routed down if ws too small)
// EPI 3: out[row] = gateval[row]*acc (shared down; writes full out)
template<int EPI, bool GATHER>
__global__ __launch_bounds__(256, 3)
void gemm3(const unsigned short* __restrict__ A, int lda,
           const float* __restrict__ B, size_t eStrideB, int ldb, int K,
           int Mfixed, const int* __restrict__ counts, const int* __restrict__ offsets,
           const int* __restrict__ tlist, const float* __restrict__ wlist,
           unsigned short* __restrict__ C, int ldc,
           const float* __restrict__ gateval, float* __restrict__ out, int ldout) {
    __shared__ s16x8 As[2][512];      // [buf][g(=k/8)*128 + row], 16B cells
    __shared__ float Bsf[2][4096];    // [buf][g2(=k/4)*512 + row*4], 16B cells

    int e = blockIdx.z;
    int M = counts ? counts[e] : Mfixed;
    int n0 = blockIdx.x * BN;         // N fast-varying (round-1 order)
    int m0 = blockIdx.y * BM;
    if (M == 0 || m0 >= M) return;
    int row_off = offsets ? offsets[e] : 0;
    const float* Bp = B + (size_t)e * eStrideB;

    int tid = threadIdx.x;
    int lane = tid & 63, w = tid >> 6;

    // A staging: wave w = k-group w (8 bf16); lane covers row it*64+lane
    const unsigned short* aptr[2];
    #pragma unroll
    for (int it = 0; it < 2; ++it) {
        int ar = m0 + it * 64 + lane; if (ar > M - 1) ar = M - 1;
        size_t grow;
        if constexpr (GATHER) grow = (size_t)tlist[e * TT + ar];
        else                  grow = (size_t)(row_off + ar);
        aptr[it] = A + grow * (size_t)lda;
    }
    // B staging: per-lane row pointer; wave w covers k-groups-of-4 {2w, 2w+1}
    const float* bptr = Bp + (size_t)(n0 + lane) * ldb;

    int wm = (w >> 1) * 64, wn = (w & 1) * 64;
    int grp = lane >> 4, l16 = lane & 15;

    f32x4 acc[4][4];
    f32x4 zero = {0.f, 0.f, 0.f, 0.f};
    #pragma unroll
    for (int mi = 0; mi < 4; ++mi)
        #pragma unroll
        for (int ni = 0; ni < 4; ++ni) acc[mi][ni] = zero;

    auto stage = [&](int buf, int k0) {
        #pragma unroll
        for (int it = 0; it < 2; ++it)
            gload16(aptr[it] + k0 + w * 8, (void*)&As[buf][w * 128 + it * 64]);
        #pragma unroll
        for (int j = 0; j < 4; ++j) {
            int g2 = w * 2 + (j & 1), r0 = (j >> 1) * 64;
            gload16(bptr + (size_t)r0 * ldb + g2 * 4 + k0,
                    (void*)&Bsf[buf][g2 * 512 + r0 * 4]);
        }
    };

    stage(0, 0);
    int NT = K / BK;
    for (int kt = 0; kt < NT; ++kt) {
        int cur = kt & 1;
        __syncthreads();                              // vmcnt(0) drain + barrier
        if (kt + 1 < NT) stage(cur ^ 1, (kt + 1) * BK);
        s16x8 af[4];
        #pragma unroll
        for (int i = 0; i < 4; ++i) af[i] = As[cur][grp * 128 + wm + i * 16 + l16];
        #pragma unroll
        for (int ni = 0; ni < 4; ++ni) {
            const float* c0 = &Bsf[cur][(2 * grp) * 512 + (wn + ni * 16 + l16) * 4];
            f32x4 h0 = *(const f32x4*)c0;             // ds_read_b128
            f32x4 h1 = *(const f32x4*)(c0 + 512);     // ds_read_b128
            s16x8 bfr = pack8(h0, h1);
            #pragma unroll
            for (int mi = 0; mi < 4; ++mi)
                acc[mi][ni] = __builtin_amdgcn_mfma_f32_16x16x32_bf16(af[mi], bfr, acc[mi][ni], 0, 0, 0);
        }
    }

    // epilogue: frag row = (lane>>4)*4 + r, col = lane&15
    #pragma unroll
    for (int mi = 0; mi < 4; ++mi) {
        #pragma unroll
        for (int r = 0; r < 4; ++r) {
            int mrow = m0 + wm + mi * 16 + (lane >> 4) * 4 + r;
            if (mrow >= M) continue;
            #pragma unroll
            for (int ni = 0; ni < 4; ++ni) {
                int col = n0 + wn + ni * 16 + l16;
                float v = acc[mi][ni][r];
                if constexpr (EPI == 0) {
                    C[(size_t)(row_off + mrow) * ldc + col] = f2bf(v);
                } else if constexpr (EPI == 1) {
                    size_t idx = (size_t)(row_off + mrow) * ldc + col;
                    float g = bf2f(C[idx]);
                    C[idx] = f2bf(g * v / (1.f + __expf(-g)));
                } else if constexpr (EPI == 2) {
                    int tok = tlist[e * TT + mrow]; float wv = wlist[e * TT + mrow];
                    atomicAdd(out + (size_t)tok * ldout + col, wv * v);
                } else {
                    out[(size_t)mrow * ldout + col] = gateval[mrow] * v;
                }
            }
        }
    }
}

extern "C" void kernel_launch(void* const* d_in, const int* in_sizes, int n_in,
                              void* d_out, int out_size, void* d_ws, size_t ws_size,
                              hipStream_t stream) {
    const float* x    = (const float*)d_in[0];
    const float* gw   = (const float*)d_in[1];
    const float* gpw  = (const float*)d_in[2];
    const float* upw  = (const float*)d_in[3];
    const float* dpw  = (const float*)d_in[4];
    const float* sgw  = (const float*)d_in[5];
    const float* suw  = (const float*)d_in[6];
    const float* sdw  = (const float*)d_in[7];
    const float* segw = (const float*)d_in[8];
    float* out = (float*)d_out;
    char* ws = (char*)d_ws;

    int*   counts  = (int*)(ws + 0);
    int*   offsets = (int*)(ws + 64);
    int*   tlist   = (int*)(ws + 256);        // 64 KB
    float* wlist   = (float*)(ws + 65792);    // 64 KB
    float* gateval = (float*)(ws + 131328);   // 8 KB
    int*   selpos  = (int*)(ws + 139520);     // 16 KB
    unsigned short* xb    = (unsigned short*)(ws + 155904);     // 8 MB bf16 activations
    unsigned short* gbuf  = (unsigned short*)(ws + 8544512);    // 23.1 MB (shared) / 11.5 MB (routed)
    unsigned short* robuf = (unsigned short*)(ws + 20078848);   // 16.8 MB
    size_t needed = 20078848 + (size_t)4096 * HD * 2;           // ~36.9 MB

    hipMemsetAsync(counts, 0, 64, stream);
    cvt_kernel<<<dim3(TT * HD / (256 * 8)), 256, 0, stream>>>(x, xb);
    router_kernel<<<dim3(TT / 4), 256, 0, stream>>>(x, gw, segw, counts, tlist, wlist, gateval, selpos);
    prefix_kernel<<<dim3(1), 64, 0, stream>>>(counts, offsets);

    // shared expert: gate -> gbuf, up (SwiGLU RMW) -> gbuf, gated down -> out
    gemm3<0, false><<<dim3(SFD / BN, TT / BM, 1), 256, 0, stream>>>(
        xb, HD, sgw, 0, HD, HD, TT, nullptr, nullptr, nullptr, nullptr, gbuf, SFD, nullptr, nullptr, 0);
    gemm3<1, false><<<dim3(SFD / BN, TT / BM, 1), 256, 0, stream>>>(
        xb, HD, suw, 0, HD, HD, TT, nullptr, nullptr, nullptr, nullptr, gbuf, SFD, nullptr, nullptr, 0);
    gemm3<3, false><<<dim3(HD / BN, TT / BM, 1), 256, 0, stream>>>(
        gbuf, SFD, sdw, 0, SFD, SFD, TT, nullptr, nullptr, nullptr, nullptr, nullptr, 0, gateval, out, HD);

    // routed experts: gate -> gbuf, up (SwiGLU RMW) -> gbuf (expert-sorted rows)
    gemm3<0, true><<<dim3(FD / BN, TT / BM, NE), 256, 0, stream>>>(
        xb, HD, gpw, (size_t)FD * HD, HD, HD, 0, counts, offsets, tlist, nullptr, gbuf, FD, nullptr, nullptr, 0);
    gemm3<1, true><<<dim3(FD / BN, TT / BM, NE), 256, 0, stream>>>(
        xb, HD, upw, (size_t)FD * HD, HD, HD, 0, counts, offsets, tlist, nullptr, gbuf, FD, nullptr, nullptr, 0);

    if (ws_size >= needed) {
        // down -> robuf (no atomics), then per-token combine (out +=)
        gemm3<0, false><<<dim3(HD / BN, TT / BM, NE), 256, 0, stream>>>(
            gbuf, FD, dpw, (size_t)HD * FD, FD, FD, 0, counts, offsets, nullptr, nullptr, robuf, HD, nullptr, nullptr, 0);
        combine_kernel<<<dim3(TT), 256, 0, stream>>>(selpos, wlist, offsets, robuf, out);
    } else {
        // fallback: atomic scatter-add
        gemm3<2, false><<<dim3(HD / BN, TT / BM, NE), 256, 0, stream>>>(
            gbuf, FD, dpw, (size_t)HD * FD, FD, FD, 0, counts, offsets, tlist, wlist, nullptr, 0, nullptr, out, HD);
    }
}

// Round 5
// 886.440 us; speedup vs baseline: 1.8096x; 1.2832x over previous
//
#include <hip/hip_runtime.h>

#define TT 2048      // tokens (B*S)
#define HD 2048      // hidden
#define FD 1408      // per-expert ffn
#define SFD 5632     // shared ffn
#define NE 8         // experts
#define BM 128
#define BN 128
#define BK 32

using f32x4 = __attribute__((ext_vector_type(4))) float;
using s16x8 = __attribute__((ext_vector_type(8))) short;

__device__ __forceinline__ unsigned short f2bf(float f) {
    union { float f; unsigned u; } v; v.f = f;
    unsigned r = v.u + 0x7fff + ((v.u >> 16) & 1);   // RNE
    return (unsigned short)(r >> 16);
}
__device__ __forceinline__ float bf2f(unsigned short u) {
    union { unsigned u; float f; } v; v.u = ((unsigned)u) << 16;
    return v.f;
}
// pack two fp32 -> bf16x2 (round-half-up, err <= 0.5 ulp)
__device__ __forceinline__ unsigned cvt2(float a, float b) {
    union { float f; unsigned u; } va, vb; va.f = a; vb.f = b;
    unsigned ra = va.u + 0x8000u, rb = vb.u + 0x8000u;
    return (rb & 0xffff0000u) | (ra >> 16);
}
__device__ __forceinline__ s16x8 pack8(f32x4 h0, f32x4 h1) {
    union { unsigned u[4]; s16x8 s; } r;
    r.u[0] = cvt2(h0[0], h0[1]); r.u[1] = cvt2(h0[2], h0[3]);
    r.u[2] = cvt2(h1[0], h1[1]); r.u[3] = cvt2(h1[2], h1[3]);
    return r.s;
}

__device__ __forceinline__ void gload16(const void* g, void* l) {
    __builtin_amdgcn_global_load_lds(
        (const __attribute__((address_space(1))) unsigned*)g,
        (__attribute__((address_space(3))) unsigned*)l, 16, 0, 0);
}

// ---- fp32 -> bf16 activation conversion -------------------------------------
__global__ void cvt_kernel(const float* __restrict__ x, unsigned short* __restrict__ xb) {
    size_t i = ((size_t)blockIdx.x * 256 + threadIdx.x) * 8;
    float4 f0 = *(const float4*)(x + i);
    float4 f1 = *(const float4*)(x + i + 4);
    s16x8 v;
    v[0]=(short)f2bf(f0.x); v[1]=(short)f2bf(f0.y); v[2]=(short)f2bf(f0.z); v[3]=(short)f2bf(f0.w);
    v[4]=(short)f2bf(f1.x); v[5]=(short)f2bf(f1.y); v[6]=(short)f2bf(f1.z); v[7]=(short)f2bf(f1.w);
    *(s16x8*)(xb + i) = v;
}

// ---- router: fp32 softmax, top-2, expert lists, shared sigmoid gate ---------
__global__ void router_kernel(const float* __restrict__ x, const float* __restrict__ gw,
                              const float* __restrict__ segw,
                              int* counts, int* tlist, float* wlist, float* gateval,
                              int* selpos) {
    int wave = threadIdx.x >> 6;
    int lane = threadIdx.x & 63;
    int t = blockIdx.x * 4 + wave;
    float acc[9];
    #pragma unroll
    for (int i = 0; i < 9; ++i) acc[i] = 0.f;
    const float* xrow = x + (size_t)t * HD;
    for (int h = lane; h < HD; h += 64) {
        float xv = xrow[h];
        #pragma unroll
        for (int e = 0; e < NE; ++e) acc[e] += xv * gw[e * HD + h];
        acc[8] += xv * segw[h];
    }
    #pragma unroll
    for (int i = 0; i < 9; ++i) {
        float v = acc[i];
        #pragma unroll
        for (int s = 32; s > 0; s >>= 1) v += __shfl_xor(v, s);
        acc[i] = v;
    }
    if (lane == 0) {
        float m = acc[0];
        #pragma unroll
        for (int e = 1; e < NE; ++e) m = fmaxf(m, acc[e]);
        float p[NE], sum = 0.f;
        #pragma unroll
        for (int e = 0; e < NE; ++e) { p[e] = expf(acc[e] - m); sum += p[e]; }
        float inv = 1.f / sum;
        int b1 = 0, b2 = -1; float v1 = p[0], v2 = -1.f;
        #pragma unroll
        for (int e = 1; e < NE; ++e) {
            if (p[e] > v1) { v2 = v1; b2 = b1; v1 = p[e]; b1 = e; }
            else if (p[e] > v2) { v2 = p[e]; b2 = e; }
        }
        v1 *= inv; v2 *= inv;
        int s1 = atomicAdd(&counts[b1], 1); tlist[b1 * TT + s1] = t; wlist[b1 * TT + s1] = v1;
        int s2 = atomicAdd(&counts[b2], 1); tlist[b2 * TT + s2] = t; wlist[b2 * TT + s2] = v2;
        selpos[2 * t]     = b1 * TT + s1;
        selpos[2 * t + 1] = b2 * TT + s2;
        gateval[t] = 1.f / (1.f + expf(-acc[8]));
    }
}

__global__ void prefix_kernel(const int* counts, int* offsets) {
    if (threadIdx.x == 0) {
        int s = 0;
        for (int e = 0; e < NE; ++e) { offsets[e] = s; s += counts[e]; }
    }
}

// ---- combine: out[t] += w0*robuf[row0] + w1*robuf[row1] ---------------------
__global__ void combine_kernel(const int* __restrict__ selpos, const float* __restrict__ wlist,
                               const int* __restrict__ offsets,
                               const unsigned short* __restrict__ robuf, float* __restrict__ out) {
    int t = blockIdx.x;
    int p0 = selpos[2 * t], p1 = selpos[2 * t + 1];
    float w0 = wlist[p0], w1 = wlist[p1];
    int r0 = offsets[p0 >> 11] + (p0 & (TT - 1));
    int r1 = offsets[p1 >> 11] + (p1 & (TT - 1));
    int c = threadIdx.x * 8;
    s16x8 a = *(const s16x8*)(robuf + (size_t)r0 * HD + c);
    s16x8 b = *(const s16x8*)(robuf + (size_t)r1 * HD + c);
    float* op = out + (size_t)t * HD + c;
    float4 o0 = *(float4*)op, o1 = *(float4*)(op + 4);
    o0.x += w0 * bf2f((unsigned short)a[0]) + w1 * bf2f((unsigned short)b[0]);
    o0.y += w0 * bf2f((unsigned short)a[1]) + w1 * bf2f((unsigned short)b[1]);
    o0.z += w0 * bf2f((unsigned short)a[2]) + w1 * bf2f((unsigned short)b[2]);
    o0.w += w0 * bf2f((unsigned short)a[3]) + w1 * bf2f((unsigned short)b[3]);
    o1.x += w0 * bf2f((unsigned short)a[4]) + w1 * bf2f((unsigned short)b[4]);
    o1.y += w0 * bf2f((unsigned short)a[5]) + w1 * bf2f((unsigned short)b[5]);
    o1.z += w0 * bf2f((unsigned short)a[6]) + w1 * bf2f((unsigned short)b[6]);
    o1.w += w0 * bf2f((unsigned short)a[7]) + w1 * bf2f((unsigned short)b[7]);
    *(float4*)op = o0; *(float4*)(op + 4) = o1;
}

// ---- GEMM: C[M,N] = A[M,K](bf16) @ B[N,K](fp32)^T ---------------------------
// Wave-contiguous staging via global_load_lds:
//   A LDS = [row][k0..31] (64B rows); one instr = 16 rows, lane l -> row l>>2,
//   chunk (l&3)^(row&3) (source-side XOR swizzle, m173).
//   B LDS = [row][k0..31] (128B rows fp32); one instr = 8 rows, lane l -> row l>>3,
//   chunk (l&7)^(row&7). Frag reads apply the same XOR: B conflict-free, A 4-way.
// Depth-2 pipeline: 3 LDS buffers, raw s_barrier + counted s_waitcnt vmcnt(12)
// (never drains to 0 mid-loop; stage(k) issued 2 iterations ahead of use).
// fp32->bf16 at fragment build (round-half-up pack).
// EPI 0: C = bf16(acc)               (gate store; also routed down -> robuf)
// EPI 1: C = bf16(silu(C)*acc)       (up, SwiGLU RMW in-place)
// EPI 2: atomicAdd out[tok] += w*acc (fallback routed down if ws too small)
// EPI 3: out[row] = gateval[row]*acc (shared down; writes full out)
template<int EPI, bool GATHER>
__global__ __launch_bounds__(256, 2)
void gemm4(const unsigned short* __restrict__ A, int lda,
           const float* __restrict__ B, size_t eStrideB, int ldb, int K,
           int Mfixed, const int* __restrict__ counts, const int* __restrict__ offsets,
           const int* __restrict__ tlist, const float* __restrict__ wlist,
           unsigned short* __restrict__ C, int ldc,
           const float* __restrict__ gateval, float* __restrict__ out, int ldout) {
    __shared__ s16x8 As[3][512];      // 3 x 8KB:  [row*4 + slot]
    __shared__ f32x4 Bs[3][1024];     // 3 x 16KB: [row*8 + slot]

    int e = blockIdx.z;
    int M = counts ? counts[e] : Mfixed;
    int n0 = blockIdx.x * BN;         // N fast-varying
    int m0 = blockIdx.y * BM;
    if (M == 0 || m0 >= M) return;
    int row_off = offsets ? offsets[e] : 0;
    const float* Bp = B + (size_t)e * eStrideB;

    int tid = threadIdx.x;
    int lane = tid & 63, w = tid >> 6;

    // A staging: 2 instrs/thread; instr j covers tile rows [32w+16j, +16)
    const unsigned short* aptr[2];
    #pragma unroll
    for (int j = 0; j < 2; ++j) {
        int r = 32 * w + 16 * j + (lane >> 2);          // tile-local row
        int c = (lane & 3) ^ (r & 3);                   // swizzled source chunk
        int ar = m0 + r; if (ar > M - 1) ar = M - 1;
        size_t grow;
        if constexpr (GATHER) grow = (size_t)tlist[e * TT + ar];
        else                  grow = (size_t)(row_off + ar);
        aptr[j] = A + grow * (size_t)lda + c * 8;       // 16B chunk = 8 bf16
    }
    // B staging: 4 instrs/thread; instr j covers tile rows [32w+8j, +8)
    const float* bptr[4];
    #pragma unroll
    for (int j = 0; j < 4; ++j) {
        int r = 32 * w + 8 * j + (lane >> 3);
        int c = (lane & 7) ^ (r & 7);
        bptr[j] = Bp + (size_t)(n0 + r) * ldb + c * 4;  // 16B chunk = 4 floats
    }

    int wm = (w >> 1) * 64, wn = (w & 1) * 64;
    int grp = lane >> 4, l16 = lane & 15;

    f32x4 acc[4][4];
    f32x4 zero = {0.f, 0.f, 0.f, 0.f};
    #pragma unroll
    for (int mi = 0; mi < 4; ++mi)
        #pragma unroll
        for (int ni = 0; ni < 4; ++ni) acc[mi][ni] = zero;

    auto stage = [&](int buf, int k0) {
        #pragma unroll
        for (int j = 0; j < 2; ++j)
            gload16(aptr[j] + k0, (void*)&As[buf][(32 * w + 16 * j) * 4]);
        #pragma unroll
        for (int j = 0; j < 4; ++j)
            gload16(bptr[j] + k0, (void*)&Bs[buf][(32 * w + 8 * j) * 8]);
    };

    int NT = K / BK;                   // >= 44 for all shapes
    stage(0, 0);
    stage(1, BK);
    for (int kt = 0; kt < NT; ++kt) {
        int cur = kt % 3;
        __builtin_amdgcn_s_barrier();              // buf[(kt+2)%3] reads (step kt-1) done
        if (kt + 2 < NT) {
            stage((kt + 2) % 3, (kt + 2) * BK);
            asm volatile("s_waitcnt vmcnt(12)" ::: "memory");   // stage(kt) landed
        } else if (kt + 1 < NT) {
            asm volatile("s_waitcnt vmcnt(6)" ::: "memory");
        } else {
            asm volatile("s_waitcnt vmcnt(0)" ::: "memory");
        }
        s16x8 af[4];
        #pragma unroll
        for (int mi = 0; mi < 4; ++mi) {
            int rr = wm + mi * 16 + l16;
            af[mi] = As[cur][rr * 4 + (grp ^ (rr & 3))];
        }
        #pragma unroll
        for (int ni = 0; ni < 4; ++ni) {
            int rb = wn + ni * 16 + l16;
            int s0 = (2 * grp) ^ (rb & 7);
            f32x4 h0 = Bs[cur][rb * 8 + s0];
            f32x4 h1 = Bs[cur][rb * 8 + (s0 ^ 1)];
            s16x8 bfr = pack8(h0, h1);
            #pragma unroll
            for (int mi = 0; mi < 4; ++mi)
                acc[mi][ni] = __builtin_amdgcn_mfma_f32_16x16x32_bf16(af[mi], bfr, acc[mi][ni], 0, 0, 0);
        }
    }

    // epilogue: frag row = (lane>>4)*4 + r, col = lane&15
    #pragma unroll
    for (int mi = 0; mi < 4; ++mi) {
        #pragma unroll
        for (int r = 0; r < 4; ++r) {
            int mrow = m0 + wm + mi * 16 + (lane >> 4) * 4 + r;
            if (mrow >= M) continue;
            #pragma unroll
            for (int ni = 0; ni < 4; ++ni) {
                int col = n0 + wn + ni * 16 + l16;
                float v = acc[mi][ni][r];
                if constexpr (EPI == 0) {
                    C[(size_t)(row_off + mrow) * ldc + col] = f2bf(v);
                } else if constexpr (EPI == 1) {
                    size_t idx = (size_t)(row_off + mrow) * ldc + col;
                    float g = bf2f(C[idx]);
                    C[idx] = f2bf(g * v / (1.f + __expf(-g)));
                } else if constexpr (EPI == 2) {
                    int tok = tlist[e * TT + mrow]; float wv = wlist[e * TT + mrow];
                    atomicAdd(out + (size_t)tok * ldout + col, wv * v);
                } else {
                    out[(size_t)mrow * ldout + col] = gateval[mrow] * v;
                }
            }
        }
    }
}

extern "C" void kernel_launch(void* const* d_in, const int* in_sizes, int n_in,
                              void* d_out, int out_size, void* d_ws, size_t ws_size,
                              hipStream_t stream) {
    const float* x    = (const float*)d_in[0];
    const float* gw   = (const float*)d_in[1];
    const float* gpw  = (const float*)d_in[2];
    const float* upw  = (const float*)d_in[3];
    const float* dpw  = (const float*)d_in[4];
    const float* sgw  = (const float*)d_in[5];
    const float* suw  = (const float*)d_in[6];
    const float* sdw  = (const float*)d_in[7];
    const float* segw = (const float*)d_in[8];
    float* out = (float*)d_out;
    char* ws = (char*)d_ws;

    int*   counts  = (int*)(ws + 0);
    int*   offsets = (int*)(ws + 64);
    int*   tlist   = (int*)(ws + 256);        // 64 KB
    float* wlist   = (float*)(ws + 65792);    // 64 KB
    float* gateval = (float*)(ws + 131328);   // 8 KB
    int*   selpos  = (int*)(ws + 139520);     // 16 KB
    unsigned short* xb    = (unsigned short*)(ws + 155904);     // 8 MB bf16 activations
    unsigned short* gbuf  = (unsigned short*)(ws + 8544512);    // 23.1 MB (shared) / 11.5 MB (routed)
    unsigned short* robuf = (unsigned short*)(ws + 20078848);   // 16.8 MB
    size_t needed = 20078848 + (size_t)4096 * HD * 2;           // ~36.9 MB

    hipMemsetAsync(counts, 0, 64, stream);
    cvt_kernel<<<dim3(TT * HD / (256 * 8)), 256, 0, stream>>>(x, xb);
    router_kernel<<<dim3(TT / 4), 256, 0, stream>>>(x, gw, segw, counts, tlist, wlist, gateval, selpos);
    prefix_kernel<<<dim3(1), 64, 0, stream>>>(counts, offsets);

    // shared expert: gate -> gbuf, up (SwiGLU RMW) -> gbuf, gated down -> out
    gemm4<0, false><<<dim3(SFD / BN, TT / BM, 1), 256, 0, stream>>>(
        xb, HD, sgw, 0, HD, HD, TT, nullptr, nullptr, nullptr, nullptr, gbuf, SFD, nullptr, nullptr, 0);
    gemm4<1, false><<<dim3(SFD / BN, TT / BM, 1), 256, 0, stream>>>(
        xb, HD, suw, 0, HD, HD, TT, nullptr, nullptr, nullptr, nullptr, gbuf, SFD, nullptr, nullptr, 0);
    gemm4<3, false><<<dim3(HD / BN, TT / BM, 1), 256, 0, stream>>>(
        gbuf, SFD, sdw, 0, SFD, SFD, TT, nullptr, nullptr, nullptr, nullptr, nullptr, 0, gateval, out, HD);

    // routed experts: gate -> gbuf, up (SwiGLU RMW) -> gbuf (expert-sorted rows)
    gemm4<0, true><<<dim3(FD / BN, TT / BM, NE), 256, 0, stream>>>(
        xb, HD, gpw, (size_t)FD * HD, HD, HD, 0, counts, offsets, tlist, nullptr, gbuf, FD, nullptr, nullptr, 0);
    gemm4<1, true><<<dim3(FD / BN, TT / BM, NE), 256, 0, stream>>>(
        xb, HD, upw, (size_t)FD * HD, HD, HD, 0, counts, offsets, tlist, nullptr, gbuf, FD, nullptr, nullptr, 0);

    if (ws_size >= needed) {
        // down -> robuf (no atomics), then per-token combine (out +=)
        gemm4<0, false><<<dim3(HD / BN, TT / BM, NE), 256, 0, stream>>>(
            gbuf, FD, dpw, (size_t)HD * FD, FD, FD, 0, counts, offsets, nullptr, nullptr, robuf, HD, nullptr, nullptr, 0);
        combine_kernel<<<dim3(TT), 256, 0, stream>>>(selpos, wlist, offsets, robuf, out);
    } else {
        // fallback: atomic scatter-add
        gemm4<2, false><<<dim3(HD / BN, TT / BM, NE), 256, 0, stream>>>(
            gbuf, FD, dpw, (size_t)HD * FD, FD, FD, 0, counts, offsets, tlist, wlist, nullptr, 0, nullptr, out, HD);
    }
}

// Round 6
// 577.718 us; speedup vs baseline: 2.7766x; 1.5344x over previous
//
#include <hip/hip_runtime.h>

#define TT 2048      // tokens (B*S)
#define HD 2048      // hidden
#define FD 1408      // per-expert ffn
#define SFD 5632     // shared ffn
#define NE 8         // experts
#define BM 128
#define BN 128
#define BK 32

using f32x4 = __attribute__((ext_vector_type(4))) float;
using s16x8 = __attribute__((ext_vector_type(8))) short;
typedef unsigned short us;

__device__ __forceinline__ us f2bf(float f) {
    union { float f; unsigned u; } v; v.f = f;
    unsigned r = v.u + 0x7fff + ((v.u >> 16) & 1);   // RNE
    return (us)(r >> 16);
}
__device__ __forceinline__ float bf2f(us u) {
    union { unsigned u; float f; } v; v.u = ((unsigned)u) << 16;
    return v.f;
}
// pack two fp32 -> bf16x2 (round-half-up, err <= 0.5 ulp)
__device__ __forceinline__ unsigned cvt2(float a, float b) {
    union { float f; unsigned u; } va, vb; va.f = a; vb.f = b;
    unsigned ra = va.u + 0x8000u, rb = vb.u + 0x8000u;
    return (rb & 0xffff0000u) | (ra >> 16);
}
__device__ __forceinline__ s16x8 pack8(f32x4 h0, f32x4 h1) {
    union { unsigned u[4]; s16x8 s; } r;
    r.u[0] = cvt2(h0[0], h0[1]); r.u[1] = cvt2(h0[2], h0[3]);
    r.u[2] = cvt2(h1[0], h1[1]); r.u[3] = cvt2(h1[2], h1[3]);
    return r.s;
}

__device__ __forceinline__ void gload16(const void* g, void* l) {
    __builtin_amdgcn_global_load_lds(
        (const __attribute__((address_space(1))) unsigned*)g,
        (__attribute__((address_space(3))) unsigned*)l, 16, 0, 0);
}

// ---- fp32 -> bf16 conversion (x and weights) --------------------------------
__global__ void cvt_kernel(const float* __restrict__ x, us* __restrict__ xb) {
    size_t i = ((size_t)blockIdx.x * 256 + threadIdx.x) * 8;
    float4 f0 = *(const float4*)(x + i);
    float4 f1 = *(const float4*)(x + i + 4);
    s16x8 v;
    v[0]=(short)f2bf(f0.x); v[1]=(short)f2bf(f0.y); v[2]=(short)f2bf(f0.z); v[3]=(short)f2bf(f0.w);
    v[4]=(short)f2bf(f1.x); v[5]=(short)f2bf(f1.y); v[6]=(short)f2bf(f1.z); v[7]=(short)f2bf(f1.w);
    *(s16x8*)(xb + i) = v;
}

// ---- router ------------------------------------------------------------------
__global__ void router_kernel(const float* __restrict__ x, const float* __restrict__ gw,
                              const float* __restrict__ segw,
                              int* counts, int* tlist, float* wlist, float* gateval,
                              int* selpos) {
    int wave = threadIdx.x >> 6;
    int lane = threadIdx.x & 63;
    int t = blockIdx.x * 4 + wave;
    float acc[9];
    #pragma unroll
    for (int i = 0; i < 9; ++i) acc[i] = 0.f;
    const float* xrow = x + (size_t)t * HD;
    for (int h = lane; h < HD; h += 64) {
        float xv = xrow[h];
        #pragma unroll
        for (int e = 0; e < NE; ++e) acc[e] += xv * gw[e * HD + h];
        acc[8] += xv * segw[h];
    }
    #pragma unroll
    for (int i = 0; i < 9; ++i) {
        float v = acc[i];
        #pragma unroll
        for (int s = 32; s > 0; s >>= 1) v += __shfl_xor(v, s);
        acc[i] = v;
    }
    if (lane == 0) {
        float m = acc[0];
        #pragma unroll
        for (int e = 1; e < NE; ++e) m = fmaxf(m, acc[e]);
        float p[NE], sum = 0.f;
        #pragma unroll
        for (int e = 0; e < NE; ++e) { p[e] = expf(acc[e] - m); sum += p[e]; }
        float inv = 1.f / sum;
        int b1 = 0, b2 = -1; float v1 = p[0], v2 = -1.f;
        #pragma unroll
        for (int e = 1; e < NE; ++e) {
            if (p[e] > v1) { v2 = v1; b2 = b1; v1 = p[e]; b1 = e; }
            else if (p[e] > v2) { v2 = p[e]; b2 = e; }
        }
        v1 *= inv; v2 *= inv;
        int s1 = atomicAdd(&counts[b1], 1); tlist[b1 * TT + s1] = t; wlist[b1 * TT + s1] = v1;
        int s2 = atomicAdd(&counts[b2], 1); tlist[b2 * TT + s2] = t; wlist[b2 * TT + s2] = v2;
        selpos[2 * t]     = b1 * TT + s1;
        selpos[2 * t + 1] = b2 * TT + s2;
        gateval[t] = 1.f / (1.f + expf(-acc[8]));
    }
}

__global__ void prefix_kernel(const int* counts, int* offsets) {
    if (threadIdx.x == 0) {
        int s = 0;
        for (int e = 0; e < NE; ++e) { offsets[e] = s; s += counts[e]; }
    }
}

// ---- combine (main path): out = gv*(sd0+sd1) + w0*r0 + w1*r1 ----------------
__global__ void combine_full(const int* __restrict__ selpos, const float* __restrict__ wlist,
                             const int* __restrict__ offsets, const float* __restrict__ gateval,
                             const float* __restrict__ sdpart, const us* __restrict__ robuf,
                             float* __restrict__ out) {
    int t = blockIdx.x;
    int p0 = selpos[2 * t], p1 = selpos[2 * t + 1];
    float w0 = wlist[p0], w1 = wlist[p1];
    int r0 = offsets[p0 >> 11] + (p0 & (TT - 1));
    int r1 = offsets[p1 >> 11] + (p1 & (TT - 1));
    float g = gateval[t];
    int c = threadIdx.x * 8;
    const float* s0 = sdpart + (size_t)t * HD + c;
    const float* s1 = sdpart + (size_t)TT * HD + (size_t)t * HD + c;
    s16x8 a = *(const s16x8*)(robuf + (size_t)r0 * HD + c);
    s16x8 b = *(const s16x8*)(robuf + (size_t)r1 * HD + c);
    float* op = out + (size_t)t * HD + c;
    #pragma unroll
    for (int j = 0; j < 8; ++j)
        op[j] = g * (s0[j] + s1[j]) + w0 * bf2f((us)a[j]) + w1 * bf2f((us)b[j]);
}

// ---- combine (fallback path): out += w0*r0 + w1*r1 --------------------------
__global__ void combine_add(const int* __restrict__ selpos, const float* __restrict__ wlist,
                            const int* __restrict__ offsets,
                            const us* __restrict__ robuf, float* __restrict__ out) {
    int t = blockIdx.x;
    int p0 = selpos[2 * t], p1 = selpos[2 * t + 1];
    float w0 = wlist[p0], w1 = wlist[p1];
    int r0 = offsets[p0 >> 11] + (p0 & (TT - 1));
    int r1 = offsets[p1 >> 11] + (p1 & (TT - 1));
    int c = threadIdx.x * 8;
    s16x8 a = *(const s16x8*)(robuf + (size_t)r0 * HD + c);
    s16x8 b = *(const s16x8*)(robuf + (size_t)r1 * HD + c);
    float* op = out + (size_t)t * HD + c;
    #pragma unroll
    for (int j = 0; j < 8; ++j)
        op[j] += w0 * bf2f((us)a[j]) + w1 * bf2f((us)b[j]);
}

// =============================================================================
// gemm5 (main path): all-bf16 mega-GEMM, m97 loop, 32KB LDS, 2-way swizzle.
// MODE 0 (GATE):  z=0 shared-gate (N=SFD, C=gbuf_s), z=1..8 routed-gate e=z-1
//                 (N=FD, A gathered via tlist, C=gbuf_r at offsets[e]). store.
// MODE 1 (UP):    same shapes; epilogue RMW: C = bf16(silu(C)*acc).
// MODE 2 (DOWN):  z=0..1 shared-down K-slice z (K=SFD/2, A=gbuf_s, B=sdw_b,
//                 C=sdpart[z] fp32); z=2..9 routed-down e=z-2 (K=FD, A=gbuf_r,
//                 B=dpw_b[e], C=robuf bf16).
// LDS tiles [128 rows][32 k] bf16, row = 4x16B slots, slot s holds mem-chunk
// s^((row>>1)&3)  -> frag ds_read_b128 lands 2-way on banks (free, m136).
// =============================================================================
template<int MODE>
__global__ __launch_bounds__(256, 3)
void gemm5(const us* __restrict__ Ashared, const us* __restrict__ Arouted,
           const us* __restrict__ Bshared, const us* __restrict__ Brouted,
           void* __restrict__ Cshared, us* __restrict__ Crouted,
           const int* __restrict__ counts, const int* __restrict__ offsets,
           const int* __restrict__ tlist) {
    __shared__ s16x8 Asl[2][512];   // 2 x 8KB
    __shared__ s16x8 Bsl[2][512];   // 2 x 8KB

    constexpr bool GU = (MODE < 2);
    int z = blockIdx.z;
    bool sp = GU ? (z == 0) : (z < 2);
    int e = GU ? z - 1 : z - 2;                       // valid when !sp
    int M = sp ? TT : counts[e];
    int nmax = GU ? (sp ? SFD : FD) : HD;
    int n0 = blockIdx.x * BN;
    if (n0 >= nmax) return;
    int m0 = blockIdx.y * BM;
    if (M == 0 || m0 >= M) return;
    int row_off = sp ? 0 : offsets[e];
    int NT = GU ? (HD / BK) : (sp ? (SFD / 2 / BK) : (FD / BK));
    int lda = GU ? HD : (sp ? SFD : FD);
    int ldb = GU ? HD : (sp ? SFD : FD);
    int kofs = (!GU && sp) ? z * (SFD / 2) : 0;       // element offset into K dim
    const us* Abase = (sp ? Ashared : Arouted) + kofs;
    const us* Bbase = (sp ? Bshared
                          : Brouted + (size_t)e * (GU ? (size_t)FD * HD : (size_t)HD * FD)) + kofs;

    int tid = threadIdx.x;
    int lane = tid & 63, w = tid >> 6;

    // staging pointers: instr j covers tile rows [32w+16j, +16); lane -> row l>>2,
    // source chunk (l&3)^((row>>1)&3) (inverse swizzle; LDS dest is linear)
    const us* aptr[2];
    const us* bptr[2];
    #pragma unroll
    for (int j = 0; j < 2; ++j) {
        int r = 32 * w + 16 * j + (lane >> 2);
        int c = (lane & 3) ^ ((r >> 1) & 3);
        int ar = m0 + r; if (ar > M - 1) ar = M - 1;
        size_t arow;
        if (GU && !sp) arow = (size_t)tlist[e * TT + ar];
        else if (sp)   arow = (size_t)ar;
        else           arow = (size_t)(row_off + ar);
        aptr[j] = Abase + arow * lda + c * 8;
        bptr[j] = Bbase + (size_t)(n0 + r) * ldb + c * 8;
    }

    int wm = (w >> 1) * 64, wn = (w & 1) * 64;
    int grp = lane >> 4, l16 = lane & 15;

    f32x4 acc[4][4];
    f32x4 zero = {0.f, 0.f, 0.f, 0.f};
    #pragma unroll
    for (int mi = 0; mi < 4; ++mi)
        #pragma unroll
        for (int ni = 0; ni < 4; ++ni) acc[mi][ni] = zero;

    auto stage = [&](int buf, int k0) {
        #pragma unroll
        for (int j = 0; j < 2; ++j)
            gload16(aptr[j] + k0, (void*)&Asl[buf][(32 * w + 16 * j) * 4]);
        #pragma unroll
        for (int j = 0; j < 2; ++j)
            gload16(bptr[j] + k0, (void*)&Bsl[buf][(32 * w + 16 * j) * 4]);
    };

    stage(0, 0);
    int cur = 0;
    for (int kt = 0; kt < NT; ++kt) {
        __syncthreads();                      // drains vmcnt/lgkm (m97 structure)
        if (kt + 1 < NT) stage(cur ^ 1, (kt + 1) * BK);
        s16x8 af[4];
        #pragma unroll
        for (int mi = 0; mi < 4; ++mi) {
            int rr = wm + mi * 16 + l16;
            af[mi] = Asl[cur][rr * 4 + (grp ^ ((rr >> 1) & 3))];
        }
        #pragma unroll
        for (int ni = 0; ni < 4; ++ni) {
            int rb = wn + ni * 16 + l16;
            s16x8 bf = Bsl[cur][rb * 4 + (grp ^ ((rb >> 1) & 3))];
            #pragma unroll
            for (int mi = 0; mi < 4; ++mi)
                acc[mi][ni] = __builtin_amdgcn_mfma_f32_16x16x32_bf16(af[mi], bf, acc[mi][ni], 0, 0, 0);
        }
        cur ^= 1;
    }

    // epilogue: frag row = (lane>>4)*4 + r_, col = lane&15
    #pragma unroll
    for (int mi = 0; mi < 4; ++mi) {
        #pragma unroll
        for (int r_ = 0; r_ < 4; ++r_) {
            int mrow = m0 + wm + mi * 16 + (lane >> 4) * 4 + r_;
            if (mrow >= M) continue;
            #pragma unroll
            for (int ni = 0; ni < 4; ++ni) {
                int col = n0 + wn + ni * 16 + l16;
                float v = acc[mi][ni][r_];
                if constexpr (MODE == 0) {
                    if (sp) ((us*)Cshared)[(size_t)mrow * SFD + col] = f2bf(v);
                    else    Crouted[(size_t)(row_off + mrow) * FD + col] = f2bf(v);
                } else if constexpr (MODE == 1) {
                    if (sp) {
                        size_t idx = (size_t)mrow * SFD + col;
                        float g = bf2f(((us*)Cshared)[idx]);
                        ((us*)Cshared)[idx] = f2bf(g * v / (1.f + __expf(-g)));
                    } else {
                        size_t idx = (size_t)(row_off + mrow) * FD + col;
                        float g = bf2f(Crouted[idx]);
                        Crouted[idx] = f2bf(g * v / (1.f + __expf(-g)));
                    }
                } else {
                    if (sp) ((float*)Cshared)[(size_t)z * TT * HD + (size_t)mrow * HD + col] = v;
                    else    Crouted[(size_t)(row_off + mrow) * HD + col] = f2bf(v);
                }
            }
        }
    }
}

// =============================================================================
// gemm4 (fallback path, round-5 proven): fp32 B staged via global_load_lds.
// =============================================================================
template<int EPI, bool GATHER>
__global__ __launch_bounds__(256, 2)
void gemm4(const us* __restrict__ A, int lda,
           const float* __restrict__ B, size_t eStrideB, int ldb, int K,
           int Mfixed, const int* __restrict__ counts, const int* __restrict__ offsets,
           const int* __restrict__ tlist, const float* __restrict__ wlist,
           us* __restrict__ C, int ldc,
           const float* __restrict__ gateval, float* __restrict__ out, int ldout) {
    __shared__ s16x8 As[3][512];
    __shared__ f32x4 Bs[3][1024];

    int e = blockIdx.z;
    int M = counts ? counts[e] : Mfixed;
    int n0 = blockIdx.x * BN;
    int m0 = blockIdx.y * BM;
    if (M == 0 || m0 >= M) return;
    int row_off = offsets ? offsets[e] : 0;
    const float* Bp = B + (size_t)e * eStrideB;

    int tid = threadIdx.x;
    int lane = tid & 63, w = tid >> 6;

    const us* aptr[2];
    #pragma unroll
    for (int j = 0; j < 2; ++j) {
        int r = 32 * w + 16 * j + (lane >> 2);
        int c = (lane & 3) ^ (r & 3);
        int ar = m0 + r; if (ar > M - 1) ar = M - 1;
        size_t grow;
        if constexpr (GATHER) grow = (size_t)tlist[e * TT + ar];
        else                  grow = (size_t)(row_off + ar);
        aptr[j] = A + grow * (size_t)lda + c * 8;
    }
    const float* bptr[4];
    #pragma unroll
    for (int j = 0; j < 4; ++j) {
        int r = 32 * w + 8 * j + (lane >> 3);
        int c = (lane & 7) ^ (r & 7);
        bptr[j] = Bp + (size_t)(n0 + r) * ldb + c * 4;
    }

    int wm = (w >> 1) * 64, wn = (w & 1) * 64;
    int grp = lane >> 4, l16 = lane & 15;

    f32x4 acc[4][4];
    f32x4 zero = {0.f, 0.f, 0.f, 0.f};
    #pragma unroll
    for (int mi = 0; mi < 4; ++mi)
        #pragma unroll
        for (int ni = 0; ni < 4; ++ni) acc[mi][ni] = zero;

    auto stage = [&](int buf, int k0) {
        #pragma unroll
        for (int j = 0; j < 2; ++j)
            gload16(aptr[j] + k0, (void*)&As[buf][(32 * w + 16 * j) * 4]);
        #pragma unroll
        for (int j = 0; j < 4; ++j)
            gload16(bptr[j] + k0, (void*)&Bs[buf][(32 * w + 8 * j) * 8]);
    };

    int NT = K / BK;
    stage(0, 0);
    stage(1, BK);
    for (int kt = 0; kt < NT; ++kt) {
        int cur = kt % 3;
        __builtin_amdgcn_s_barrier();
        if (kt + 2 < NT) {
            stage((kt + 2) % 3, (kt + 2) * BK);
            asm volatile("s_waitcnt vmcnt(12)" ::: "memory");
        } else if (kt + 1 < NT) {
            asm volatile("s_waitcnt vmcnt(6)" ::: "memory");
        } else {
            asm volatile("s_waitcnt vmcnt(0)" ::: "memory");
        }
        s16x8 af[4];
        #pragma unroll
        for (int mi = 0; mi < 4; ++mi) {
            int rr = wm + mi * 16 + l16;
            af[mi] = As[cur][rr * 4 + (grp ^ (rr & 3))];
        }
        #pragma unroll
        for (int ni = 0; ni < 4; ++ni) {
            int rb = wn + ni * 16 + l16;
            int s0 = (2 * grp) ^ (rb & 7);
            f32x4 h0 = Bs[cur][rb * 8 + s0];
            f32x4 h1 = Bs[cur][rb * 8 + (s0 ^ 1)];
            s16x8 bfr = pack8(h0, h1);
            #pragma unroll
            for (int mi = 0; mi < 4; ++mi)
                acc[mi][ni] = __builtin_amdgcn_mfma_f32_16x16x32_bf16(af[mi], bfr, acc[mi][ni], 0, 0, 0);
        }
    }

    #pragma unroll
    for (int mi = 0; mi < 4; ++mi) {
        #pragma unroll
        for (int r_ = 0; r_ < 4; ++r_) {
            int mrow = m0 + wm + mi * 16 + (lane >> 4) * 4 + r_;
            if (mrow >= M) continue;
            #pragma unroll
            for (int ni = 0; ni < 4; ++ni) {
                int col = n0 + wn + ni * 16 + l16;
                float v = acc[mi][ni][r_];
                if constexpr (EPI == 0) {
                    C[(size_t)(row_off + mrow) * ldc + col] = f2bf(v);
                } else if constexpr (EPI == 1) {
                    size_t idx = (size_t)(row_off + mrow) * ldc + col;
                    float g = bf2f(C[idx]);
                    C[idx] = f2bf(g * v / (1.f + __expf(-g)));
                } else if constexpr (EPI == 2) {
                    int tok = tlist[e * TT + mrow]; float wv = wlist[e * TT + mrow];
                    atomicAdd(out + (size_t)tok * ldout + col, wv * v);
                } else {
                    out[(size_t)mrow * ldout + col] = gateval[mrow] * v;
                }
            }
        }
    }
}

extern "C" void kernel_launch(void* const* d_in, const int* in_sizes, int n_in,
                              void* d_out, int out_size, void* d_ws, size_t ws_size,
                              hipStream_t stream) {
    const float* x    = (const float*)d_in[0];
    const float* gw   = (const float*)d_in[1];
    const float* gpw  = (const float*)d_in[2];
    const float* upw  = (const float*)d_in[3];
    const float* dpw  = (const float*)d_in[4];
    const float* sgw  = (const float*)d_in[5];
    const float* suw  = (const float*)d_in[6];
    const float* sdw  = (const float*)d_in[7];
    const float* segw = (const float*)d_in[8];
    float* out = (float*)d_out;
    char* ws = (char*)d_ws;

    int*   counts  = (int*)(ws + 0);
    int*   offsets = (int*)(ws + 64);
    int*   tlist   = (int*)(ws + 256);
    float* wlist   = (float*)(ws + 65792);
    float* gateval = (float*)(ws + 131328);
    int*   selpos  = (int*)(ws + 139520);

    hipMemsetAsync(counts, 0, 64, stream);
    router_kernel<<<dim3(TT / 4), 256, 0, stream>>>(x, gw, segw, counts, tlist, wlist, gateval, selpos);
    prefix_kernel<<<dim3(1), 64, 0, stream>>>(counts, offsets);

    // ---------------- main path: bf16 weights + mega-dispatches ----------------
    size_t need_main = 301203456ull;   // layout below
    if (ws_size >= need_main) {
        us* xb     = (us*)(ws + 262144);          //   8.4 MB
        us* gpw_b  = (us*)(ws + 8650752);         //  46.1 MB
        us* upw_b  = (us*)(ws + 54788096);        //  46.1 MB
        us* dpw_b  = (us*)(ws + 100925440);       //  46.1 MB
        us* sgw_b  = (us*)(ws + 147062784);       //  23.1 MB
        us* suw_b  = (us*)(ws + 170131456);       //  23.1 MB
        us* sdw_b  = (us*)(ws + 193200128);       //  23.1 MB
        us* gbuf_s = (us*)(ws + 216268800);       //  23.1 MB
        us* gbuf_r = (us*)(ws + 239337472);       //  11.5 MB
        us* robuf  = (us*)(ws + 250871808);       //  16.8 MB
        float* sdpart = (float*)(ws + 267649024); //  33.6 MB (2 fp32 partials)

        cvt_kernel<<<dim3(TT * HD / 2048), 256, 0, stream>>>(x, xb);
        cvt_kernel<<<dim3(NE * FD * HD / 2048), 256, 0, stream>>>(gpw, gpw_b);
        cvt_kernel<<<dim3(NE * FD * HD / 2048), 256, 0, stream>>>(upw, upw_b);
        cvt_kernel<<<dim3(NE * HD * FD / 2048), 256, 0, stream>>>(dpw, dpw_b);
        cvt_kernel<<<dim3(SFD * HD / 2048), 256, 0, stream>>>(sgw, sgw_b);
        cvt_kernel<<<dim3(SFD * HD / 2048), 256, 0, stream>>>(suw, suw_b);
        cvt_kernel<<<dim3(HD * SFD / 2048), 256, 0, stream>>>(sdw, sdw_b);

        // GATE mega: z=0 shared (44x16 active), z=1..8 routed (11 x ceil(cnt/128))
        gemm5<0><<<dim3(SFD / BN, TT / BM, 1 + NE), 256, 0, stream>>>(
            xb, xb, sgw_b, gpw_b, gbuf_s, gbuf_r, counts, offsets, tlist);
        // UP mega (SwiGLU RMW)
        gemm5<1><<<dim3(SFD / BN, TT / BM, 1 + NE), 256, 0, stream>>>(
            xb, xb, suw_b, upw_b, gbuf_s, gbuf_r, counts, offsets, tlist);
        // DOWN mega: z=0..1 shared split-K fp32 partials, z=2..9 routed -> robuf
        gemm5<2><<<dim3(HD / BN, TT / BM, 2 + NE), 256, 0, stream>>>(
            gbuf_s, gbuf_r, sdw_b, dpw_b, sdpart, robuf, counts, offsets, tlist);

        combine_full<<<dim3(TT), 256, 0, stream>>>(selpos, wlist, offsets, gateval, sdpart, robuf, out);
        return;
    }

    // ---------------- fallback path (round-5, proven) --------------------------
    us* xb    = (us*)(ws + 155904);
    us* gbuf  = (us*)(ws + 8544512);
    us* robuf = (us*)(ws + 20078848);
    size_t need_fb = 20078848 + (size_t)4096 * HD * 2;

    cvt_kernel<<<dim3(TT * HD / 2048), 256, 0, stream>>>(x, xb);

    gemm4<0, false><<<dim3(SFD / BN, TT / BM, 1), 256, 0, stream>>>(
        xb, HD, sgw, 0, HD, HD, TT, nullptr, nullptr, nullptr, nullptr, gbuf, SFD, nullptr, nullptr, 0);
    gemm4<1, false><<<dim3(SFD / BN, TT / BM, 1), 256, 0, stream>>>(
        xb, HD, suw, 0, HD, HD, TT, nullptr, nullptr, nullptr, nullptr, gbuf, SFD, nullptr, nullptr, 0);
    gemm4<3, false><<<dim3(HD / BN, TT / BM, 1), 256, 0, stream>>>(
        gbuf, SFD, sdw, 0, SFD, SFD, TT, nullptr, nullptr, nullptr, nullptr, nullptr, 0, gateval, out, HD);

    gemm4<0, true><<<dim3(FD / BN, TT / BM, NE), 256, 0, stream>>>(
        xb, HD, gpw, (size_t)FD * HD, HD, HD, 0, counts, offsets, tlist, nullptr, gbuf, FD, nullptr, nullptr, 0);
    gemm4<1, true><<<dim3(FD / BN, TT / BM, NE), 256, 0, stream>>>(
        xb, HD, upw, (size_t)FD * HD, HD, HD, 0, counts, offsets, tlist, nullptr, gbuf, FD, nullptr, nullptr, 0);

    if (ws_size >= need_fb) {
        gemm4<0, false><<<dim3(HD / BN, TT / BM, NE), 256, 0, stream>>>(
            gbuf, FD, dpw, (size_t)HD * FD, FD, FD, 0, counts, offsets, nullptr, nullptr, robuf, HD, nullptr, nullptr, 0);
        combine_add<<<dim3(TT), 256, 0, stream>>>(selpos, wlist, offsets, robuf, out);
    } else {
        gemm4<2, false><<<dim3(HD / BN, TT / BM, NE), 256, 0, stream>>>(
            gbuf, FD, dpw, (size_t)HD * FD, FD, FD, 0, counts, offsets, tlist, wlist, nullptr, 0, nullptr, out, HD);
    }
}

// Round 7
// 502.709 us; speedup vs baseline: 3.1909x; 1.1492x over previous
//
#include <hip/hip_runtime.h>

#define TT 2048      // tokens (B*S)
#define HD 2048      // hidden
#define FD 1408      // per-expert ffn
#define SFD 5632     // shared ffn
#define NE 8         // experts
#define BM 128
#define BN 128
#define BK 32

using f32x4 = __attribute__((ext_vector_type(4))) float;
using s16x8 = __attribute__((ext_vector_type(8))) short;
typedef unsigned short us;

__device__ __forceinline__ us f2bf(float f) {
    union { float f; unsigned u; } v; v.f = f;
    unsigned r = v.u + 0x7fff + ((v.u >> 16) & 1);   // RNE
    return (us)(r >> 16);
}
__device__ __forceinline__ float bf2f(us u) {
    union { unsigned u; float f; } v; v.u = ((unsigned)u) << 16;
    return v.f;
}
// pack two fp32 -> bf16x2 (round-half-up, err <= 0.5 ulp)
__device__ __forceinline__ unsigned cvt2(float a, float b) {
    union { float f; unsigned u; } va, vb; va.f = a; vb.f = b;
    unsigned ra = va.u + 0x8000u, rb = vb.u + 0x8000u;
    return (rb & 0xffff0000u) | (ra >> 16);
}
__device__ __forceinline__ s16x8 pack8(f32x4 h0, f32x4 h1) {
    union { unsigned u[4]; s16x8 s; } r;
    r.u[0] = cvt2(h0[0], h0[1]); r.u[1] = cvt2(h0[2], h0[3]);
    r.u[2] = cvt2(h1[0], h1[1]); r.u[3] = cvt2(h1[2], h1[3]);
    return r.s;
}

__device__ __forceinline__ void gload16(const void* g, void* l) {
    __builtin_amdgcn_global_load_lds(
        (const __attribute__((address_space(1))) unsigned*)g,
        (__attribute__((address_space(3))) unsigned*)l, 16, 0, 0);
}

// ---- fp32 -> bf16 conversion (x and weights) --------------------------------
__global__ void cvt_kernel(const float* __restrict__ x, us* __restrict__ xb) {
    size_t i = ((size_t)blockIdx.x * 256 + threadIdx.x) * 8;
    float4 f0 = *(const float4*)(x + i);
    float4 f1 = *(const float4*)(x + i + 4);
    s16x8 v;
    v[0]=(short)f2bf(f0.x); v[1]=(short)f2bf(f0.y); v[2]=(short)f2bf(f0.z); v[3]=(short)f2bf(f0.w);
    v[4]=(short)f2bf(f1.x); v[5]=(short)f2bf(f1.y); v[6]=(short)f2bf(f1.z); v[7]=(short)f2bf(f1.w);
    *(s16x8*)(xb + i) = v;
}

// ---- router ------------------------------------------------------------------
__global__ void router_kernel(const float* __restrict__ x, const float* __restrict__ gw,
                              const float* __restrict__ segw,
                              int* counts, int* tlist, float* wlist, float* gateval,
                              int* selpos) {
    int wave = threadIdx.x >> 6;
    int lane = threadIdx.x & 63;
    int t = blockIdx.x * 4 + wave;
    float acc[9];
    #pragma unroll
    for (int i = 0; i < 9; ++i) acc[i] = 0.f;
    const float* xrow = x + (size_t)t * HD;
    for (int h = lane; h < HD; h += 64) {
        float xv = xrow[h];
        #pragma unroll
        for (int e = 0; e < NE; ++e) acc[e] += xv * gw[e * HD + h];
        acc[8] += xv * segw[h];
    }
    #pragma unroll
    for (int i = 0; i < 9; ++i) {
        float v = acc[i];
        #pragma unroll
        for (int s = 32; s > 0; s >>= 1) v += __shfl_xor(v, s);
        acc[i] = v;
    }
    if (lane == 0) {
        float m = acc[0];
        #pragma unroll
        for (int e = 1; e < NE; ++e) m = fmaxf(m, acc[e]);
        float p[NE], sum = 0.f;
        #pragma unroll
        for (int e = 0; e < NE; ++e) { p[e] = expf(acc[e] - m); sum += p[e]; }
        float inv = 1.f / sum;
        int b1 = 0, b2 = -1; float v1 = p[0], v2 = -1.f;
        #pragma unroll
        for (int e = 1; e < NE; ++e) {
            if (p[e] > v1) { v2 = v1; b2 = b1; v1 = p[e]; b1 = e; }
            else if (p[e] > v2) { v2 = p[e]; b2 = e; }
        }
        v1 *= inv; v2 *= inv;
        int s1 = atomicAdd(&counts[b1], 1); tlist[b1 * TT + s1] = t; wlist[b1 * TT + s1] = v1;
        int s2 = atomicAdd(&counts[b2], 1); tlist[b2 * TT + s2] = t; wlist[b2 * TT + s2] = v2;
        selpos[2 * t]     = b1 * TT + s1;
        selpos[2 * t + 1] = b2 * TT + s2;
        gateval[t] = 1.f / (1.f + expf(-acc[8]));
    }
}

__global__ void prefix_kernel(const int* counts, int* offsets) {
    if (threadIdx.x == 0) {
        int s = 0;
        for (int e = 0; e < NE; ++e) { offsets[e] = s; s += counts[e]; }
    }
}

// ---- combine (main path): out = gv*(sd0+sd1) + w0*r0 + w1*r1 ----------------
__global__ void combine_full(const int* __restrict__ selpos, const float* __restrict__ wlist,
                             const int* __restrict__ offsets, const float* __restrict__ gateval,
                             const float* __restrict__ sdpart, const us* __restrict__ robuf,
                             float* __restrict__ out) {
    int t = blockIdx.x;
    int p0 = selpos[2 * t], p1 = selpos[2 * t + 1];
    float w0 = wlist[p0], w1 = wlist[p1];
    int r0 = offsets[p0 >> 11] + (p0 & (TT - 1));
    int r1 = offsets[p1 >> 11] + (p1 & (TT - 1));
    float g = gateval[t];
    int c = threadIdx.x * 8;
    const float* s0 = sdpart + (size_t)t * HD + c;
    const float* s1 = sdpart + (size_t)TT * HD + (size_t)t * HD + c;
    s16x8 a = *(const s16x8*)(robuf + (size_t)r0 * HD + c);
    s16x8 b = *(const s16x8*)(robuf + (size_t)r1 * HD + c);
    float* op = out + (size_t)t * HD + c;
    #pragma unroll
    for (int j = 0; j < 8; ++j)
        op[j] = g * (s0[j] + s1[j]) + w0 * bf2f((us)a[j]) + w1 * bf2f((us)b[j]);
}

// ---- combine (fallback path): out += w0*r0 + w1*r1 --------------------------
__global__ void combine_add(const int* __restrict__ selpos, const float* __restrict__ wlist,
                            const int* __restrict__ offsets,
                            const us* __restrict__ robuf, float* __restrict__ out) {
    int t = blockIdx.x;
    int p0 = selpos[2 * t], p1 = selpos[2 * t + 1];
    float w0 = wlist[p0], w1 = wlist[p1];
    int r0 = offsets[p0 >> 11] + (p0 & (TT - 1));
    int r1 = offsets[p1 >> 11] + (p1 & (TT - 1));
    int c = threadIdx.x * 8;
    s16x8 a = *(const s16x8*)(robuf + (size_t)r0 * HD + c);
    s16x8 b = *(const s16x8*)(robuf + (size_t)r1 * HD + c);
    float* op = out + (size_t)t * HD + c;
    #pragma unroll
    for (int j = 0; j < 8; ++j)
        op[j] += w0 * bf2f((us)a[j]) + w1 * bf2f((us)b[j]);
}

// =============================================================================
// gemm6: FUSED gate+up mega-GEMM (bf16, m97 loop, dual accumulators).
// z=0: shared (A=xb, N=SFD, B=sgw_b/suw_b, C=gbuf_s)
// z=1..8: routed e=z-1 (A=xb gathered, N=FD, B=gpw_b/upw_b[e], C=gbuf_r)
// Epilogue: C = bf16(silu(gate)*up)  — single write, no RMW pass.
// LDS 48 KB (A + B0 + B1, double-buffered), 3 blocks/CU.
// =============================================================================
__global__ __launch_bounds__(256, 3)
void gemm6(const us* __restrict__ xb,
           const us* __restrict__ Bg_s, const us* __restrict__ Bu_s,
           const us* __restrict__ Bg_r, const us* __restrict__ Bu_r,
           us* __restrict__ Cs, us* __restrict__ Cr,
           const int* __restrict__ counts, const int* __restrict__ offsets,
           const int* __restrict__ tlist) {
    __shared__ s16x8 Asl[2][512];
    __shared__ s16x8 B0l[2][512];
    __shared__ s16x8 B1l[2][512];

    int z = blockIdx.z;
    bool sp = (z == 0);
    int e = z - 1;
    int M = sp ? TT : counts[e];
    int nmax = sp ? SFD : FD;
    int n0 = blockIdx.x * BN;
    if (n0 >= nmax) return;
    int m0 = blockIdx.y * BM;
    if (M == 0 || m0 >= M) return;
    int row_off = sp ? 0 : offsets[e];
    const us* B0p = sp ? Bg_s : Bg_r + (size_t)e * FD * HD;
    const us* B1p = sp ? Bu_s : Bu_r + (size_t)e * FD * HD;

    int tid = threadIdx.x;
    int lane = tid & 63, w = tid >> 6;

    // staging: instr j covers tile rows [32w+16j, +16); lane -> row l>>2,
    // source chunk (l&3)^((row>>1)&3) (2-way swizzle; LDS dest linear)
    const us* aptr[2];
    const us* b0ptr[2];
    const us* b1ptr[2];
    #pragma unroll
    for (int j = 0; j < 2; ++j) {
        int r = 32 * w + 16 * j + (lane >> 2);
        int c = (lane & 3) ^ ((r >> 1) & 3);
        int ar = m0 + r; if (ar > M - 1) ar = M - 1;
        size_t arow = sp ? (size_t)ar : (size_t)tlist[e * TT + ar];
        aptr[j]  = xb + arow * HD + c * 8;
        b0ptr[j] = B0p + (size_t)(n0 + r) * HD + c * 8;
        b1ptr[j] = B1p + (size_t)(n0 + r) * HD + c * 8;
    }

    int wm = (w >> 1) * 64, wn = (w & 1) * 64;
    int grp = lane >> 4, l16 = lane & 15;

    f32x4 acc0[4][4], acc1[4][4];
    f32x4 zero = {0.f, 0.f, 0.f, 0.f};
    #pragma unroll
    for (int mi = 0; mi < 4; ++mi)
        #pragma unroll
        for (int ni = 0; ni < 4; ++ni) { acc0[mi][ni] = zero; acc1[mi][ni] = zero; }

    auto stage = [&](int buf, int k0) {
        #pragma unroll
        for (int j = 0; j < 2; ++j)
            gload16(aptr[j] + k0, (void*)&Asl[buf][(32 * w + 16 * j) * 4]);
        #pragma unroll
        for (int j = 0; j < 2; ++j)
            gload16(b0ptr[j] + k0, (void*)&B0l[buf][(32 * w + 16 * j) * 4]);
        #pragma unroll
        for (int j = 0; j < 2; ++j)
            gload16(b1ptr[j] + k0, (void*)&B1l[buf][(32 * w + 16 * j) * 4]);
    };

    stage(0, 0);
    int cur = 0;
    const int NT = HD / BK;
    for (int kt = 0; kt < NT; ++kt) {
        __syncthreads();
        if (kt + 1 < NT) stage(cur ^ 1, (kt + 1) * BK);
        s16x8 af[4];
        #pragma unroll
        for (int mi = 0; mi < 4; ++mi) {
            int rr = wm + mi * 16 + l16;
            af[mi] = Asl[cur][rr * 4 + (grp ^ ((rr >> 1) & 3))];
        }
        #pragma unroll
        for (int ni = 0; ni < 4; ++ni) {
            int rb = wn + ni * 16 + l16;
            int slot = rb * 4 + (grp ^ ((rb >> 1) & 3));
            s16x8 b0 = B0l[cur][slot];
            #pragma unroll
            for (int mi = 0; mi < 4; ++mi)
                acc0[mi][ni] = __builtin_amdgcn_mfma_f32_16x16x32_bf16(af[mi], b0, acc0[mi][ni], 0, 0, 0);
            s16x8 b1 = B1l[cur][slot];
            #pragma unroll
            for (int mi = 0; mi < 4; ++mi)
                acc1[mi][ni] = __builtin_amdgcn_mfma_f32_16x16x32_bf16(af[mi], b1, acc1[mi][ni], 0, 0, 0);
        }
        cur ^= 1;
    }

    #pragma unroll
    for (int mi = 0; mi < 4; ++mi) {
        #pragma unroll
        for (int r_ = 0; r_ < 4; ++r_) {
            int mrow = m0 + wm + mi * 16 + (lane >> 4) * 4 + r_;
            if (mrow >= M) continue;
            #pragma unroll
            for (int ni = 0; ni < 4; ++ni) {
                int col = n0 + wn + ni * 16 + l16;
                float g = acc0[mi][ni][r_], u = acc1[mi][ni][r_];
                float val = g * u / (1.f + __expf(-g));
                if (sp) Cs[(size_t)mrow * SFD + col] = f2bf(val);
                else    Cr[(size_t)(row_off + mrow) * FD + col] = f2bf(val);
            }
        }
    }
}

// =============================================================================
// gemm5<2>: DOWN mega (unchanged from round 6).
// z=0..1 shared-down K-slice z (K=SFD/2, A=gbuf_s, B=sdw_b, C=sdpart[z] fp32);
// z=2..9 routed-down e=z-2 (K=FD, A=gbuf_r, B=dpw_b[e], C=robuf bf16).
// =============================================================================
template<int MODE>
__global__ __launch_bounds__(256, 3)
void gemm5(const us* __restrict__ Ashared, const us* __restrict__ Arouted,
           const us* __restrict__ Bshared, const us* __restrict__ Brouted,
           void* __restrict__ Cshared, us* __restrict__ Crouted,
           const int* __restrict__ counts, const int* __restrict__ offsets,
           const int* __restrict__ tlist) {
    __shared__ s16x8 Asl[2][512];
    __shared__ s16x8 Bsl[2][512];

    int z = blockIdx.z;
    bool sp = (z < 2);
    int e = z - 2;
    int M = sp ? TT : counts[e];
    int n0 = blockIdx.x * BN;
    int m0 = blockIdx.y * BM;
    if (M == 0 || m0 >= M) return;
    int row_off = sp ? 0 : offsets[e];
    int NT = sp ? (SFD / 2 / BK) : (FD / BK);
    int lda = sp ? SFD : FD;
    int kofs = sp ? z * (SFD / 2) : 0;
    const us* Abase = (sp ? Ashared : Arouted) + kofs;
    const us* Bbase = (sp ? Bshared : Brouted + (size_t)e * HD * FD) + kofs;

    int tid = threadIdx.x;
    int lane = tid & 63, w = tid >> 6;

    const us* aptr[2];
    const us* bptr[2];
    #pragma unroll
    for (int j = 0; j < 2; ++j) {
        int r = 32 * w + 16 * j + (lane >> 2);
        int c = (lane & 3) ^ ((r >> 1) & 3);
        int ar = m0 + r; if (ar > M - 1) ar = M - 1;
        size_t arow = sp ? (size_t)ar : (size_t)(row_off + ar);
        aptr[j] = Abase + arow * lda + c * 8;
        bptr[j] = Bbase + (size_t)(n0 + r) * lda + c * 8;
    }

    int wm = (w >> 1) * 64, wn = (w & 1) * 64;
    int grp = lane >> 4, l16 = lane & 15;

    f32x4 acc[4][4];
    f32x4 zero = {0.f, 0.f, 0.f, 0.f};
    #pragma unroll
    for (int mi = 0; mi < 4; ++mi)
        #pragma unroll
        for (int ni = 0; ni < 4; ++ni) acc[mi][ni] = zero;

    auto stage = [&](int buf, int k0) {
        #pragma unroll
        for (int j = 0; j < 2; ++j)
            gload16(aptr[j] + k0, (void*)&Asl[buf][(32 * w + 16 * j) * 4]);
        #pragma unroll
        for (int j = 0; j < 2; ++j)
            gload16(bptr[j] + k0, (void*)&Bsl[buf][(32 * w + 16 * j) * 4]);
    };

    stage(0, 0);
    int cur = 0;
    for (int kt = 0; kt < NT; ++kt) {
        __syncthreads();
        if (kt + 1 < NT) stage(cur ^ 1, (kt + 1) * BK);
        s16x8 af[4];
        #pragma unroll
        for (int mi = 0; mi < 4; ++mi) {
            int rr = wm + mi * 16 + l16;
            af[mi] = Asl[cur][rr * 4 + (grp ^ ((rr >> 1) & 3))];
        }
        #pragma unroll
        for (int ni = 0; ni < 4; ++ni) {
            int rb = wn + ni * 16 + l16;
            s16x8 bf = Bsl[cur][rb * 4 + (grp ^ ((rb >> 1) & 3))];
            #pragma unroll
            for (int mi = 0; mi < 4; ++mi)
                acc[mi][ni] = __builtin_amdgcn_mfma_f32_16x16x32_bf16(af[mi], bf, acc[mi][ni], 0, 0, 0);
        }
        cur ^= 1;
    }

    #pragma unroll
    for (int mi = 0; mi < 4; ++mi) {
        #pragma unroll
        for (int r_ = 0; r_ < 4; ++r_) {
            int mrow = m0 + wm + mi * 16 + (lane >> 4) * 4 + r_;
            if (mrow >= M) continue;
            #pragma unroll
            for (int ni = 0; ni < 4; ++ni) {
                int col = n0 + wn + ni * 16 + l16;
                float v = acc[mi][ni][r_];
                if (sp) ((float*)Cshared)[(size_t)z * TT * HD + (size_t)mrow * HD + col] = v;
                else    Crouted[(size_t)(row_off + mrow) * HD + col] = f2bf(v);
            }
        }
    }
}

// =============================================================================
// gemm4 (fallback path, round-5 proven): fp32 B staged via global_load_lds.
// =============================================================================
template<int EPI, bool GATHER>
__global__ __launch_bounds__(256, 2)
void gemm4(const us* __restrict__ A, int lda,
           const float* __restrict__ B, size_t eStrideB, int ldb, int K,
           int Mfixed, const int* __restrict__ counts, const int* __restrict__ offsets,
           const int* __restrict__ tlist, const float* __restrict__ wlist,
           us* __restrict__ C, int ldc,
           const float* __restrict__ gateval, float* __restrict__ out, int ldout) {
    __shared__ s16x8 As[3][512];
    __shared__ f32x4 Bs[3][1024];

    int e = blockIdx.z;
    int M = counts ? counts[e] : Mfixed;
    int n0 = blockIdx.x * BN;
    int m0 = blockIdx.y * BM;
    if (M == 0 || m0 >= M) return;
    int row_off = offsets ? offsets[e] : 0;
    const float* Bp = B + (size_t)e * eStrideB;

    int tid = threadIdx.x;
    int lane = tid & 63, w = tid >> 6;

    const us* aptr[2];
    #pragma unroll
    for (int j = 0; j < 2; ++j) {
        int r = 32 * w + 16 * j + (lane >> 2);
        int c = (lane & 3) ^ (r & 3);
        int ar = m0 + r; if (ar > M - 1) ar = M - 1;
        size_t grow;
        if constexpr (GATHER) grow = (size_t)tlist[e * TT + ar];
        else                  grow = (size_t)(row_off + ar);
        aptr[j] = A + grow * (size_t)lda + c * 8;
    }
    const float* bptr[4];
    #pragma unroll
    for (int j = 0; j < 4; ++j) {
        int r = 32 * w + 8 * j + (lane >> 3);
        int c = (lane & 7) ^ (r & 7);
        bptr[j] = Bp + (size_t)(n0 + r) * ldb + c * 4;
    }

    int wm = (w >> 1) * 64, wn = (w & 1) * 64;
    int grp = lane >> 4, l16 = lane & 15;

    f32x4 acc[4][4];
    f32x4 zero = {0.f, 0.f, 0.f, 0.f};
    #pragma unroll
    for (int mi = 0; mi < 4; ++mi)
        #pragma unroll
        for (int ni = 0; ni < 4; ++ni) acc[mi][ni] = zero;

    auto stage = [&](int buf, int k0) {
        #pragma unroll
        for (int j = 0; j < 2; ++j)
            gload16(aptr[j] + k0, (void*)&As[buf][(32 * w + 16 * j) * 4]);
        #pragma unroll
        for (int j = 0; j < 4; ++j)
            gload16(bptr[j] + k0, (void*)&Bs[buf][(32 * w + 8 * j) * 8]);
    };

    int NT = K / BK;
    stage(0, 0);
    stage(1, BK);
    for (int kt = 0; kt < NT; ++kt) {
        int cur = kt % 3;
        __builtin_amdgcn_s_barrier();
        if (kt + 2 < NT) {
            stage((kt + 2) % 3, (kt + 2) * BK);
            asm volatile("s_waitcnt vmcnt(12)" ::: "memory");
        } else if (kt + 1 < NT) {
            asm volatile("s_waitcnt vmcnt(6)" ::: "memory");
        } else {
            asm volatile("s_waitcnt vmcnt(0)" ::: "memory");
        }
        s16x8 af[4];
        #pragma unroll
        for (int mi = 0; mi < 4; ++mi) {
            int rr = wm + mi * 16 + l16;
            af[mi] = As[cur][rr * 4 + (grp ^ (rr & 3))];
        }
        #pragma unroll
        for (int ni = 0; ni < 4; ++ni) {
            int rb = wn + ni * 16 + l16;
            int s0 = (2 * grp) ^ (rb & 7);
            f32x4 h0 = Bs[cur][rb * 8 + s0];
            f32x4 h1 = Bs[cur][rb * 8 + (s0 ^ 1)];
            s16x8 bfr = pack8(h0, h1);
            #pragma unroll
            for (int mi = 0; mi < 4; ++mi)
                acc[mi][ni] = __builtin_amdgcn_mfma_f32_16x16x32_bf16(af[mi], bfr, acc[mi][ni], 0, 0, 0);
        }
    }

    #pragma unroll
    for (int mi = 0; mi < 4; ++mi) {
        #pragma unroll
        for (int r_ = 0; r_ < 4; ++r_) {
            int mrow = m0 + wm + mi * 16 + (lane >> 4) * 4 + r_;
            if (mrow >= M) continue;
            #pragma unroll
            for (int ni = 0; ni < 4; ++ni) {
                int col = n0 + wn + ni * 16 + l16;
                float v = acc[mi][ni][r_];
                if constexpr (EPI == 0) {
                    C[(size_t)(row_off + mrow) * ldc + col] = f2bf(v);
                } else if constexpr (EPI == 1) {
                    size_t idx = (size_t)(row_off + mrow) * ldc + col;
                    float g = bf2f(C[idx]);
                    C[idx] = f2bf(g * v / (1.f + __expf(-g)));
                } else if constexpr (EPI == 2) {
                    int tok = tlist[e * TT + mrow]; float wv = wlist[e * TT + mrow];
                    atomicAdd(out + (size_t)tok * ldout + col, wv * v);
                } else {
                    out[(size_t)mrow * ldout + col] = gateval[mrow] * v;
                }
            }
        }
    }
}

extern "C" void kernel_launch(void* const* d_in, const int* in_sizes, int n_in,
                              void* d_out, int out_size, void* d_ws, size_t ws_size,
                              hipStream_t stream) {
    const float* x    = (const float*)d_in[0];
    const float* gw   = (const float*)d_in[1];
    const float* gpw  = (const float*)d_in[2];
    const float* upw  = (const float*)d_in[3];
    const float* dpw  = (const float*)d_in[4];
    const float* sgw  = (const float*)d_in[5];
    const float* suw  = (const float*)d_in[6];
    const float* sdw  = (const float*)d_in[7];
    const float* segw = (const float*)d_in[8];
    float* out = (float*)d_out;
    char* ws = (char*)d_ws;

    int*   counts  = (int*)(ws + 0);
    int*   offsets = (int*)(ws + 64);
    int*   tlist   = (int*)(ws + 256);
    float* wlist   = (float*)(ws + 65792);
    float* gateval = (float*)(ws + 131328);
    int*   selpos  = (int*)(ws + 139520);

    hipMemsetAsync(counts, 0, 64, stream);
    router_kernel<<<dim3(TT / 4), 256, 0, stream>>>(x, gw, segw, counts, tlist, wlist, gateval, selpos);
    prefix_kernel<<<dim3(1), 64, 0, stream>>>(counts, offsets);

    // ---------------- main path: bf16 weights + mega-dispatches ----------------
    size_t need_main = 301203456ull;
    if (ws_size >= need_main) {
        us* xb     = (us*)(ws + 262144);          //   8.4 MB
        us* gpw_b  = (us*)(ws + 8650752);         //  46.1 MB
        us* upw_b  = (us*)(ws + 54788096);        //  46.1 MB
        us* dpw_b  = (us*)(ws + 100925440);       //  46.1 MB
        us* sgw_b  = (us*)(ws + 147062784);       //  23.1 MB
        us* suw_b  = (us*)(ws + 170131456);       //  23.1 MB
        us* sdw_b  = (us*)(ws + 193200128);       //  23.1 MB
        us* gbuf_s = (us*)(ws + 216268800);       //  23.1 MB
        us* gbuf_r = (us*)(ws + 239337472);       //  11.5 MB
        us* robuf  = (us*)(ws + 250871808);       //  16.8 MB
        float* sdpart = (float*)(ws + 267649024); //  33.6 MB (2 fp32 partials)

        cvt_kernel<<<dim3(TT * HD / 2048), 256, 0, stream>>>(x, xb);
        cvt_kernel<<<dim3(NE * FD * HD / 2048), 256, 0, stream>>>(gpw, gpw_b);
        cvt_kernel<<<dim3(NE * FD * HD / 2048), 256, 0, stream>>>(upw, upw_b);
        cvt_kernel<<<dim3(NE * HD * FD / 2048), 256, 0, stream>>>(dpw, dpw_b);
        cvt_kernel<<<dim3(SFD * HD / 2048), 256, 0, stream>>>(sgw, sgw_b);
        cvt_kernel<<<dim3(SFD * HD / 2048), 256, 0, stream>>>(suw, suw_b);
        cvt_kernel<<<dim3(HD * SFD / 2048), 256, 0, stream>>>(sdw, sdw_b);

        // FUSED gate+up mega: z=0 shared, z=1..8 routed; silu epilogue, no RMW
        gemm6<<<dim3(SFD / BN, TT / BM, 1 + NE), 256, 0, stream>>>(
            xb, sgw_b, suw_b, gpw_b, upw_b, gbuf_s, gbuf_r, counts, offsets, tlist);
        // DOWN mega: z=0..1 shared split-K fp32 partials, z=2..9 routed -> robuf
        gemm5<2><<<dim3(HD / BN, TT / BM, 2 + NE), 256, 0, stream>>>(
            gbuf_s, gbuf_r, sdw_b, dpw_b, sdpart, robuf, counts, offsets, tlist);

        combine_full<<<dim3(TT), 256, 0, stream>>>(selpos, wlist, offsets, gateval, sdpart, robuf, out);
        return;
    }

    // ---------------- fallback path (round-5, proven) --------------------------
    us* xb    = (us*)(ws + 155904);
    us* gbuf  = (us*)(ws + 8544512);
    us* robuf = (us*)(ws + 20078848);
    size_t need_fb = 20078848 + (size_t)4096 * HD * 2;

    cvt_kernel<<<dim3(TT * HD / 2048), 256, 0, stream>>>(x, xb);

    gemm4<0, false><<<dim3(SFD / BN, TT / BM, 1), 256, 0, stream>>>(
        xb, HD, sgw, 0, HD, HD, TT, nullptr, nullptr, nullptr, nullptr, gbuf, SFD, nullptr, nullptr, 0);
    gemm4<1, false><<<dim3(SFD / BN, TT / BM, 1), 256, 0, stream>>>(
        xb, HD, suw, 0, HD, HD, TT, nullptr, nullptr, nullptr, nullptr, gbuf, SFD, nullptr, nullptr, 0);
    gemm4<3, false><<<dim3(HD / BN, TT / BM, 1), 256, 0, stream>>>(
        gbuf, SFD, sdw, 0, SFD, SFD, TT, nullptr, nullptr, nullptr, nullptr, nullptr, 0, gateval, out, HD);

    gemm4<0, true><<<dim3(FD / BN, TT / BM, NE), 256, 0, stream>>>(
        xb, HD, gpw, (size_t)FD * HD, HD, HD, 0, counts, offsets, tlist, nullptr, gbuf, FD, nullptr, nullptr, 0);
    gemm4<1, true><<<dim3(FD / BN, TT / BM, NE), 256, 0, stream>>>(
        xb, HD, upw, (size_t)FD * HD, HD, HD, 0, counts, offsets, tlist, nullptr, gbuf, FD, nullptr, nullptr, 0);

    if (ws_size >= need_fb) {
        gemm4<0, false><<<dim3(HD / BN, TT / BM, NE), 256, 0, stream>>>(
            gbuf, FD, dpw, (size_t)HD * FD, FD, FD, 0, counts, offsets, nullptr, nullptr, robuf, HD, nullptr, nullptr, 0);
        combine_add<<<dim3(TT), 256, 0, stream>>>(selpos, wlist, offsets, robuf, out);
    } else {
        gemm4<2, false><<<dim3(HD / BN, TT / BM, NE), 256, 0, stream>>>(
            gbuf, FD, dpw, (size_t)HD * FD, FD, FD, 0, counts, offsets, tlist, wlist, nullptr, 0, nullptr, out, HD);
    }
}